// Round 1
// baseline (1076.323 us; speedup 1.0000x reference)
//
#include <hip/hip_runtime.h>

#define B_ 16
#define L_ 512
#define D_ 768
#define H_ 4
#define A_ 100
#define DK_ 25
#define P_ 3

// ---------------------------------------------------------------- reductions
__device__ __forceinline__ float blk_reduce_sum256(float v, float* red, int tid) {
    #pragma unroll
    for (int o = 32; o > 0; o >>= 1) v += __shfl_down(v, o);
    __syncthreads();
    if ((tid & 63) == 0) red[tid >> 6] = v;
    __syncthreads();
    return red[0] + red[1] + red[2] + red[3];
}

// ------------------------------------------------- K1: LayerNorm + x = seq@Wxx^T + b
__global__ __launch_bounds__(256) void k_ln_x(
    const float* __restrict__ seq, const float* __restrict__ ln_a, const float* __restrict__ ln_b,
    const float* __restrict__ Wxx_w, const float* __restrict__ Wxx_b, float* __restrict__ x)
{
    __shared__ float row[D_];
    __shared__ float red[4];
    const int tid = threadIdx.x;
    const int r = blockIdx.x;                      // (b*L + l)
    const float* src = seq + (size_t)r * D_;
    if (tid < 192) ((float4*)row)[tid] = ((const float4*)src)[tid];
    __syncthreads();
    float v0 = row[tid], v1 = row[tid + 256], v2 = row[tid + 512];
    float s = blk_reduce_sum256(v0 + v1 + v2, red, tid);
    float mean = s * (1.0f / 768.0f);
    float d0 = v0 - mean, d1 = v1 - mean, d2 = v2 - mean;
    float sq = blk_reduce_sum256(d0 * d0 + d1 * d1 + d2 * d2, red, tid);
    float var = sq * (1.0f / 767.0f);              // ddof=1
    float rd = 1.0f / (sqrtf(var) + 1e-6f);        // std + EPS
    row[tid]       = ln_a[tid]       * (d0 * rd) + ln_b[tid];
    row[tid + 256] = ln_a[tid + 256] * (d1 * rd) + ln_b[tid + 256];
    row[tid + 512] = ln_a[tid + 512] * (d2 * rd) + ln_b[tid + 512];
    __syncthreads();
    if (tid < A_) {
        const float4* wr = (const float4*)(Wxx_w + (size_t)tid * D_);
        const float4* rr = (const float4*)row;
        float acc = Wxx_b[tid];
        #pragma unroll 4
        for (int c = 0; c < 192; ++c) {
            float4 w = wr[c], q = rr[c];
            acc += w.x * q.x + w.y * q.y + w.z * q.z + w.w * q.w;
        }
        x[(size_t)r * A_ + tid] = acc;
    }
}

// ------------------------------------------------- K2: q/k projections -> (B,H,L,DK)
__global__ __launch_bounds__(256) void k_qk(
    const float* __restrict__ x, const float* __restrict__ q_w, const float* __restrict__ q_b,
    const float* __restrict__ k_w, const float* __restrict__ k_b,
    float* __restrict__ qt, float* __restrict__ kt)
{
    __shared__ float xs[A_];
    const int tid = threadIdx.x, r = blockIdx.x;
    const int b = r >> 9, l = r & 511;
    if (tid < A_) xs[tid] = x[(size_t)r * A_ + tid];
    __syncthreads();
    if (tid < 2 * A_) {
        const int m = tid / A_, a = tid % A_;
        const float* w = m ? k_w : q_w;
        float acc = m ? k_b[a] : q_b[a];
        #pragma unroll 4
        for (int c = 0; c < A_; ++c) acc += xs[c] * w[a * A_ + c];
        const int h = a / DK_, dk = a % DK_;
        float* dst = m ? kt : qt;
        dst[(((size_t)b * H_ + h) * L_ + l) * DK_ + dk] = acc;
    }
}

// --------------------- K3: scores + mask + syntax + softmax -> adjsum, wadj (B,L,L)
__global__ __launch_bounds__(256) void k_scores(
    const float* __restrict__ qt, const float* __restrict__ kt,
    const float* __restrict__ syn, const int* __restrict__ src_mask,
    const float* __restrict__ Wx_w,
    float* __restrict__ adjsum, float* __restrict__ wadj)
{
    __shared__ float es[H_][L_];
    __shared__ float qs[H_ * DK_];
    __shared__ float cs[H_], inv[H_];
    const int tid = threadIdx.x, r = blockIdx.x;
    const int b = r >> 9, i = r & 511;
    if (tid < A_) qs[tid] = qt[(((size_t)b * H_ + tid / DK_) * L_ + i) * DK_ + tid % DK_];
    if (tid < H_) cs[tid] = Wx_w[tid] + Wx_w[204 + tid] + Wx_w[408 + tid] + Wx_w[612 + tid];
    __syncthreads();
    for (int jj = tid; jj < L_; jj += 256) {
        const int mk = src_mask[b * L_ + jj];
        #pragma unroll
        for (int h = 0; h < H_; ++h) {
            const float* kr = kt + (((size_t)b * H_ + h) * L_ + jj) * DK_;
            float dot = 0.f;
            #pragma unroll
            for (int d = 0; d < DK_; ++d) dot += qs[h * DK_ + d] * kr[d];
            float sc = mk ? dot * 0.2f : -1e9f;     // /sqrt(25)
            es[h][jj] = sc + syn[(((size_t)b * H_ + h) * L_ + i) * L_ + jj];
        }
    }
    __syncthreads();
    const int h = tid >> 6, lane = tid & 63;
    float mx = -3.4e38f;
    for (int j = lane; j < L_; j += 64) mx = fmaxf(mx, es[h][j]);
    #pragma unroll
    for (int o = 32; o > 0; o >>= 1) mx = fmaxf(mx, __shfl_xor(mx, o));
    float sum = 0.f;
    for (int j = lane; j < L_; j += 64) { float e = __expf(es[h][j] - mx); es[h][j] = e; sum += e; }
    #pragma unroll
    for (int o = 32; o > 0; o >>= 1) sum += __shfl_xor(sum, o);
    if (lane == 0) inv[h] = 1.0f / sum;
    __syncthreads();
    for (int jj = tid; jj < L_; jj += 256) {
        float p0 = es[0][jj] * inv[0], p1 = es[1][jj] * inv[1];
        float p2 = es[2][jj] * inv[2], p3 = es[3][jj] * inv[3];
        size_t o = ((size_t)b * L_ + i) * L_ + jj;
        adjsum[o] = p0 + p1 + p2 + p3;
        wadj[o]   = cs[0] * p0 + cs[1] * p1 + cs[2] * p2 + cs[3] * p3;
    }
}

// ------------- K4: x_out = relu(((adj@xin)/H [+extras]) @ W^T + b), 4 rows per block
#define ROWS 4
template<int LAYER2>
__global__ __launch_bounds__(256) void k_ax(
    const float* __restrict__ adj, const float* __restrict__ xin,
    const float* __restrict__ W_w, const float* __restrict__ W_b,
    const float* __restrict__ S, const float* __restrict__ T,
    const float* __restrict__ Vv, const float* __restrict__ Wx_b,
    float* __restrict__ xout)
{
    __shared__ float xs[64][A_];
    __shared__ float adjs[ROWS][64];
    __shared__ float axs[ROWS][A_];
    const int tid = threadIdx.x;
    const int b = blockIdx.y, row0 = blockIdx.x * ROWS;
    const int o0 = tid;
    const int r0 = o0 / A_, a0 = o0 % A_;
    const int o1 = tid + 256;
    const bool act1 = (o1 < ROWS * A_);
    const int r1 = act1 ? o1 / A_ : 0, a1 = act1 ? o1 % A_ : 0;
    float acc0 = 0.f, acc1 = 0.f;

    for (int kc = 0; kc < L_ / 64; ++kc) {
        // stage x chunk: 64 rows x 100 floats = 1600 float4
        for (int idx = tid; idx < 64 * (A_ / 4); idx += 256) {
            int kr = idx / (A_ / 4), c4 = idx % (A_ / 4);
            ((float4*)&xs[kr][0])[c4] =
                ((const float4*)(xin + ((size_t)b * L_ + kc * 64 + kr) * A_))[c4];
        }
        {
            int ar = tid >> 6, ak = tid & 63;
            adjs[ar][ak] = adj[((size_t)b * L_ + row0 + ar) * L_ + kc * 64 + ak];
        }
        __syncthreads();
        #pragma unroll 8
        for (int k = 0; k < 64; ++k) {
            acc0 += adjs[r0][k] * xs[k][a0];
            acc1 += adjs[r1][k] * xs[k][a1];
        }
        __syncthreads();
    }

    float wb = 0.f;
    if (LAYER2) wb = Wx_b[0] + Wx_b[1] + Wx_b[2] + Wx_b[3];
    {
        float ax = acc0;
        if (LAYER2) ax += S[b * A_ + a0] + (Vv[b * L_ + row0 + r0] + wb) * T[b * A_ + a0];
        axs[r0][a0] = ax * 0.25f;                   // /H
    }
    if (act1) {
        float ax = acc1;
        if (LAYER2) ax += S[b * A_ + a1] + (Vv[b * L_ + row0 + r1] + wb) * T[b * A_ + a1];
        axs[r1][a1] = ax * 0.25f;
    }
    __syncthreads();
    {
        float out = W_b[a0];
        #pragma unroll 4
        for (int c = 0; c < A_; ++c) out += axs[r0][c] * W_w[a0 * A_ + c];
        xout[((size_t)b * L_ + row0 + r0) * A_ + a0] = fmaxf(out, 0.f);
    }
    if (act1) {
        float out = W_b[a1];
        #pragma unroll 4
        for (int c = 0; c < A_; ++c) out += axs[r1][c] * W_w[a1 * A_ + c];
        xout[((size_t)b * L_ + row0 + r1) * A_ + a1] = fmaxf(out, 0.f);
    }
}

// ---------------- K5: rank-1 extras for layer 2: Vv (B,L), T,S (B,A); zero pooled
__global__ __launch_bounds__(256) void k_extras(
    const float* __restrict__ x1, const float* __restrict__ Wx_w,
    float* __restrict__ Vv, float* __restrict__ T, float* __restrict__ S,
    float* __restrict__ pooled)
{
    __shared__ float b1s[A_], b2s[A_], Ul[L_];
    const int tid = threadIdx.x, b = blockIdx.x;
    if (tid < A_) {
        float s1 = 0.f, s2 = 0.f;
        #pragma unroll
        for (int g = 0; g < H_; ++g) {
            s1 += Wx_w[g * 204 + 4 + tid];
            s2 += Wx_w[g * 204 + 104 + tid];
        }
        b1s[tid] = s1; b2s[tid] = s2;
        pooled[b * A_ + tid] = 0.f;
    }
    __syncthreads();
    for (int j = tid; j < L_; j += 256) {
        const float* xr = x1 + ((size_t)b * L_ + j) * A_;
        float u = 0.f, v = 0.f;
        #pragma unroll 4
        for (int c = 0; c < A_; ++c) { float xv = xr[c]; u += xv * b1s[c]; v += xv * b2s[c]; }
        Ul[j] = u;
        Vv[b * L_ + j] = v;
    }
    __syncthreads();
    if (tid < A_) {
        float t = 0.f, s = 0.f;
        for (int j = 0; j < L_; ++j) {
            float xv = x1[((size_t)b * L_ + j) * A_ + tid];
            t += xv; s += Ul[j] * xv;
        }
        T[b * A_ + tid] = t; S[b * A_ + tid] = s;
    }
}

// ---------------- K6: node = relu([x,x1,x2]@agg^T + b); pooled += node (atomic)
__global__ __launch_bounds__(128) void k_node(
    const float* __restrict__ x, const float* __restrict__ x1, const float* __restrict__ x2,
    const float* __restrict__ agg_w, const float* __restrict__ agg_b,
    float* __restrict__ pooled)
{
    __shared__ float fs[3 * A_];
    const int tid = threadIdx.x, r = blockIdx.x, b = r >> 9;
    if (tid < A_) {
        fs[tid]          = x[(size_t)r * A_ + tid];
        fs[A_ + tid]     = x1[(size_t)r * A_ + tid];
        fs[2 * A_ + tid] = x2[(size_t)r * A_ + tid];
    }
    __syncthreads();
    if (tid < A_) {
        float acc = agg_b[tid];
        const float* wr = agg_w + (size_t)tid * (3 * A_);
        #pragma unroll 4
        for (int c = 0; c < 3 * A_; ++c) acc += fs[c] * wr[c];
        atomicAdd(&pooled[b * A_ + tid], fmaxf(acc, 0.f));
    }
}

// ---------------- K7: logits = (pooled/valid_len) @ cls^T + b
__global__ __launch_bounds__(64) void k_logits(
    const float* __restrict__ pooled, const float* __restrict__ cls_w,
    const float* __restrict__ cls_b, const int* __restrict__ mask_ids,
    float* __restrict__ out)
{
    const int tid = threadIdx.x;
    if (tid < B_ * P_) {
        const int b = tid / P_, p = tid % P_;
        int vs = 0;
        for (int l = 0; l < L_; ++l) vs += mask_ids[b * L_ + l];
        float inv = 1.0f / (float)max(vs, 1);
        float acc = cls_b[p];
        #pragma unroll 4
        for (int a = 0; a < A_; ++a) acc += (pooled[b * A_ + a] * inv) * cls_w[p * A_ + a];
        out[b * P_ + p] = acc;
    }
}

extern "C" void kernel_launch(void* const* d_in, const int* in_sizes, int n_in,
                              void* d_out, int out_size, void* d_ws, size_t ws_size,
                              hipStream_t stream) {
    const float* seq    = (const float*)d_in[0];
    const float* syn    = (const float*)d_in[1];
    const float* ln_a   = (const float*)d_in[2];
    const float* ln_b   = (const float*)d_in[3];
    const float* Wxx_w  = (const float*)d_in[4];
    const float* Wxx_b  = (const float*)d_in[5];
    const float* q_w    = (const float*)d_in[6];
    const float* q_b    = (const float*)d_in[7];
    const float* k_w    = (const float*)d_in[8];
    const float* k_b    = (const float*)d_in[9];
    const float* W_w    = (const float*)d_in[10];
    const float* W_b    = (const float*)d_in[11];
    const float* Wx_w   = (const float*)d_in[12];
    const float* Wx_b   = (const float*)d_in[13];
    const float* agg_w  = (const float*)d_in[14];
    const float* agg_b  = (const float*)d_in[15];
    const float* cls_w  = (const float*)d_in[16];
    const float* cls_b  = (const float*)d_in[17];
    const int* mask_ids = (const int*)d_in[18];
    const int* src_mask = (const int*)d_in[19];
    float* out = (float*)d_out;

    float* ws = (float*)d_ws;
    size_t off = 0;
    float* x      = ws + off; off += (size_t)B_ * L_ * A_;
    float* x1     = ws + off; off += (size_t)B_ * L_ * A_;
    float* x2     = ws + off; off += (size_t)B_ * L_ * A_;
    float* qt     = ws + off; off += (size_t)B_ * L_ * A_;
    float* kt     = ws + off; off += (size_t)B_ * L_ * A_;
    float* adjsum = ws + off; off += (size_t)B_ * L_ * L_;
    float* wadj   = ws + off; off += (size_t)B_ * L_ * L_;
    float* Vv     = ws + off; off += (size_t)B_ * L_;
    float* T      = ws + off; off += (size_t)B_ * A_;
    float* S      = ws + off; off += (size_t)B_ * A_;
    float* pooled = ws + off; off += (size_t)B_ * A_;

    k_ln_x<<<B_ * L_, 256, 0, stream>>>(seq, ln_a, ln_b, Wxx_w, Wxx_b, x);
    k_qk<<<B_ * L_, 256, 0, stream>>>(x, q_w, q_b, k_w, k_b, qt, kt);
    k_scores<<<B_ * L_, 256, 0, stream>>>(qt, kt, syn, src_mask, Wx_w, adjsum, wadj);
    k_ax<0><<<dim3(L_ / ROWS, B_), 256, 0, stream>>>(adjsum, x, W_w, W_b,
                                                     nullptr, nullptr, nullptr, nullptr, x1);
    k_extras<<<B_, 256, 0, stream>>>(x1, Wx_w, Vv, T, S, pooled);
    k_ax<1><<<dim3(L_ / ROWS, B_), 256, 0, stream>>>(wadj, x1, W_w, W_b, S, T, Vv, Wx_b, x2);
    k_node<<<B_ * L_, 128, 0, stream>>>(x, x1, x2, agg_w, agg_b, pooled);
    k_logits<<<1, 64, 0, stream>>>(pooled, cls_w, cls_b, mask_ids, out);
}

// Round 2
// 834.169 us; speedup vs baseline: 1.2903x; 1.2903x over previous
//
#include <hip/hip_runtime.h>

#define B_ 16
#define L_ 512
#define D_ 768
#define H_ 4
#define A_ 100
#define DK_ 25
#define P_ 3

// ------------------------------------------------- K0: wT[d][a] = Wxx_w[a][d], pad a to 128
__global__ __launch_bounds__(256) void k_wprep(const float* __restrict__ Wxx_w,
                                               float* __restrict__ wT)
{
    const int idx = blockIdx.x * 256 + threadIdx.x;     // 768*128
    const int d = idx >> 7, a = idx & 127;
    wT[idx] = (a < A_) ? Wxx_w[(size_t)a * D_ + d] : 0.f;
}

// ------------------- K1: fused LayerNorm + x = seq_ln @ Wxx^T + b  (tiled GEMM)
// block: 32 rows x 128 cols (cols 100..127 padded/dropped). 256 threads.
// thread (c4 = tid&31, rg = tid>>5): cols [4c4,4c4+4), rows rg*4..rg*4+3.
__global__ __launch_bounds__(256) void k_lnx(
    const float* __restrict__ seq, const float* __restrict__ ln_a, const float* __restrict__ ln_b,
    const float* __restrict__ wT, const float* __restrict__ Wxx_b, float* __restrict__ x)
{
    __shared__ float ss[32][36];        // [row][k] normalized seq chunk, +4 pad (b128-aligned)
    __shared__ float ws[32][128];       // [k][col] weight chunk
    __shared__ float mean_s[32], rd_s[32];
    const int tid = threadIdx.x;
    const int row0 = blockIdx.x * 32;
    const int wv = tid >> 6, lane = tid & 63;

    // --- LN stats: wave wv handles rows wv*8 .. wv*8+7
    for (int rr = 0; rr < 8; ++rr) {
        const int r = wv * 8 + rr;
        const float4* src = (const float4*)(seq + (size_t)(row0 + r) * D_);
        float4 a = src[lane], b = src[lane + 64], c = src[lane + 128];
        float s = a.x + a.y + a.z + a.w + b.x + b.y + b.z + b.w + c.x + c.y + c.z + c.w;
        #pragma unroll
        for (int o = 32; o; o >>= 1) s += __shfl_xor(s, o);
        const float m = s * (1.0f / 768.0f);
        float q = (a.x-m)*(a.x-m) + (a.y-m)*(a.y-m) + (a.z-m)*(a.z-m) + (a.w-m)*(a.w-m)
                + (b.x-m)*(b.x-m) + (b.y-m)*(b.y-m) + (b.z-m)*(b.z-m) + (b.w-m)*(b.w-m)
                + (c.x-m)*(c.x-m) + (c.y-m)*(c.y-m) + (c.z-m)*(c.z-m) + (c.w-m)*(c.w-m);
        #pragma unroll
        for (int o = 32; o; o >>= 1) q += __shfl_xor(q, o);
        if (lane == 0) {
            mean_s[r] = m;
            rd_s[r] = 1.0f / (sqrtf(q * (1.0f / 767.0f)) + 1e-6f);   // ddof=1, std+EPS
        }
    }
    __syncthreads();

    const int c4 = tid & 31, rg = tid >> 5;
    float4 acc[4];
    #pragma unroll
    for (int i = 0; i < 4; ++i) { acc[i].x = acc[i].y = acc[i].z = acc[i].w = 0.f; }

    for (int kc = 0; kc < 24; ++kc) {
        // stage normalized seq chunk: 32 rows x 32 k (256 float4, 1/thread)
        {
            const int r = tid >> 3, k4 = tid & 7;
            float4 v = *(const float4*)(seq + (size_t)(row0 + r) * D_ + kc * 32 + k4 * 4);
            float4 la = ((const float4*)ln_a)[kc * 8 + k4];
            float4 lb = ((const float4*)ln_b)[kc * 8 + k4];
            const float m = mean_s[r], rd = rd_s[r];
            float4 o;
            o.x = la.x * ((v.x - m) * rd) + lb.x;
            o.y = la.y * ((v.y - m) * rd) + lb.y;
            o.z = la.z * ((v.z - m) * rd) + lb.z;
            o.w = la.w * ((v.w - m) * rd) + lb.w;
            *(float4*)&ss[r][k4 * 4] = o;
        }
        // stage weight chunk: 32 k x 128 cols (1024 float4, 4/thread)
        #pragma unroll
        for (int t = 0; t < 4; ++t) {
            const int idx = tid + t * 256;
            const int k = idx >> 5, cc = idx & 31;
            *(float4*)&ws[k][cc * 4] = *(const float4*)(wT + (size_t)(kc * 32 + k) * 128 + cc * 4);
        }
        __syncthreads();
        #pragma unroll 2
        for (int k = 0; k < 32; k += 4) {
            float4 sv[4];
            #pragma unroll
            for (int i = 0; i < 4; ++i) sv[i] = *(float4*)&ss[rg * 4 + i][k];
            #pragma unroll
            for (int j = 0; j < 4; ++j) {
                float4 w4 = *(float4*)&ws[k + j][c4 * 4];
                #pragma unroll
                for (int i = 0; i < 4; ++i) {
                    const float sj = ((float*)&sv[i])[j];
                    acc[i].x += sj * w4.x; acc[i].y += sj * w4.y;
                    acc[i].z += sj * w4.z; acc[i].w += sj * w4.w;
                }
            }
        }
        __syncthreads();
    }

    if (c4 < 25) {
        const float4 bias = ((const float4*)Wxx_b)[c4];
        #pragma unroll
        for (int i = 0; i < 4; ++i) {
            float4 o;
            o.x = acc[i].x + bias.x; o.y = acc[i].y + bias.y;
            o.z = acc[i].z + bias.z; o.w = acc[i].w + bias.w;
            *(float4*)(x + (size_t)(row0 + rg * 4 + i) * A_ + c4 * 4) = o;
        }
    }
}

// ------------------------------------------------- K2: q/k projections -> (B,H,L,DK)
__global__ __launch_bounds__(256) void k_qk(
    const float* __restrict__ x, const float* __restrict__ q_w, const float* __restrict__ q_b,
    const float* __restrict__ k_w, const float* __restrict__ k_b,
    float* __restrict__ qt, float* __restrict__ kt)
{
    __shared__ float xs[A_];
    const int tid = threadIdx.x, r = blockIdx.x;
    const int b = r >> 9, l = r & 511;
    if (tid < A_) xs[tid] = x[(size_t)r * A_ + tid];
    __syncthreads();
    if (tid < 2 * A_) {
        const int m = tid / A_, a = tid % A_;
        const float* w = m ? k_w : q_w;
        float acc = m ? k_b[a] : q_b[a];
        #pragma unroll 4
        for (int c = 0; c < A_; ++c) acc += xs[c] * w[a * A_ + c];
        const int h = a / DK_, dk = a % DK_;
        float* dst = m ? kt : qt;
        dst[(((size_t)b * H_ + h) * L_ + l) * DK_ + dk] = acc;
    }
}

// --------------------- K3: scores + mask + syntax + softmax -> adjsum, wadj (B,L,L)
__global__ __launch_bounds__(256) void k_scores(
    const float* __restrict__ qt, const float* __restrict__ kt,
    const float* __restrict__ syn, const int* __restrict__ src_mask,
    const float* __restrict__ Wx_w,
    float* __restrict__ adjsum, float* __restrict__ wadj)
{
    __shared__ float es[H_][L_];
    __shared__ float qs[H_ * DK_];
    __shared__ float cs[H_], inv[H_];
    const int tid = threadIdx.x, r = blockIdx.x;
    const int b = r >> 9, i = r & 511;
    if (tid < A_) qs[tid] = qt[(((size_t)b * H_ + tid / DK_) * L_ + i) * DK_ + tid % DK_];
    if (tid < H_) cs[tid] = Wx_w[tid] + Wx_w[204 + tid] + Wx_w[408 + tid] + Wx_w[612 + tid];
    __syncthreads();
    for (int jj = tid; jj < L_; jj += 256) {
        const int mk = src_mask[b * L_ + jj];
        #pragma unroll
        for (int h = 0; h < H_; ++h) {
            const float* kr = kt + (((size_t)b * H_ + h) * L_ + jj) * DK_;
            float dot = 0.f;
            #pragma unroll
            for (int d = 0; d < DK_; ++d) dot += qs[h * DK_ + d] * kr[d];
            float sc = mk ? dot * 0.2f : -1e9f;     // /sqrt(25)
            es[h][jj] = sc + syn[(((size_t)b * H_ + h) * L_ + i) * L_ + jj];
        }
    }
    __syncthreads();
    const int h = tid >> 6, lane = tid & 63;
    float mx = -3.4e38f;
    for (int j = lane; j < L_; j += 64) mx = fmaxf(mx, es[h][j]);
    #pragma unroll
    for (int o = 32; o > 0; o >>= 1) mx = fmaxf(mx, __shfl_xor(mx, o));
    float sum = 0.f;
    for (int j = lane; j < L_; j += 64) { float e = __expf(es[h][j] - mx); es[h][j] = e; sum += e; }
    #pragma unroll
    for (int o = 32; o > 0; o >>= 1) sum += __shfl_xor(sum, o);
    if (lane == 0) inv[h] = 1.0f / sum;
    __syncthreads();
    for (int jj = tid; jj < L_; jj += 256) {
        float p0 = es[0][jj] * inv[0], p1 = es[1][jj] * inv[1];
        float p2 = es[2][jj] * inv[2], p3 = es[3][jj] * inv[3];
        size_t o = ((size_t)b * L_ + i) * L_ + jj;
        adjsum[o] = p0 + p1 + p2 + p3;
        wadj[o]   = cs[0] * p0 + cs[1] * p1 + cs[2] * p2 + cs[3] * p3;
    }
}

// ------------- K4: x_out = relu(((adj@xin)/H [+extras]) @ W^T + b), 4 rows per block
#define ROWS 4
template<int LAYER2>
__global__ __launch_bounds__(256) void k_ax(
    const float* __restrict__ adj, const float* __restrict__ xin,
    const float* __restrict__ W_w, const float* __restrict__ W_b,
    const float* __restrict__ S, const float* __restrict__ T,
    const float* __restrict__ Vv, const float* __restrict__ Wx_b,
    float* __restrict__ xout)
{
    __shared__ float xs[64][A_];
    __shared__ float adjs[ROWS][64];
    __shared__ float axs[ROWS][A_];
    const int tid = threadIdx.x;
    const int b = blockIdx.y, row0 = blockIdx.x * ROWS;
    const int o0 = tid;
    const int r0 = o0 / A_, a0 = o0 % A_;
    const int o1 = tid + 256;
    const bool act1 = (o1 < ROWS * A_);
    const int r1 = act1 ? o1 / A_ : 0, a1 = act1 ? o1 % A_ : 0;
    float acc0 = 0.f, acc1 = 0.f;

    for (int kc = 0; kc < L_ / 64; ++kc) {
        for (int idx = tid; idx < 64 * (A_ / 4); idx += 256) {
            int kr = idx / (A_ / 4), c4 = idx % (A_ / 4);
            ((float4*)&xs[kr][0])[c4] =
                ((const float4*)(xin + ((size_t)b * L_ + kc * 64 + kr) * A_))[c4];
        }
        {
            int ar = tid >> 6, ak = tid & 63;
            adjs[ar][ak] = adj[((size_t)b * L_ + row0 + ar) * L_ + kc * 64 + ak];
        }
        __syncthreads();
        #pragma unroll 8
        for (int k = 0; k < 64; ++k) {
            acc0 += adjs[r0][k] * xs[k][a0];
            acc1 += adjs[r1][k] * xs[k][a1];
        }
        __syncthreads();
    }

    float wb = 0.f;
    if (LAYER2) wb = Wx_b[0] + Wx_b[1] + Wx_b[2] + Wx_b[3];
    {
        float ax = acc0;
        if (LAYER2) ax += S[b * A_ + a0] + (Vv[b * L_ + row0 + r0] + wb) * T[b * A_ + a0];
        axs[r0][a0] = ax * 0.25f;
    }
    if (act1) {
        float ax = acc1;
        if (LAYER2) ax += S[b * A_ + a1] + (Vv[b * L_ + row0 + r1] + wb) * T[b * A_ + a1];
        axs[r1][a1] = ax * 0.25f;
    }
    __syncthreads();
    {
        float out = W_b[a0];
        #pragma unroll 4
        for (int c = 0; c < A_; ++c) out += axs[r0][c] * W_w[a0 * A_ + c];
        xout[((size_t)b * L_ + row0 + r0) * A_ + a0] = fmaxf(out, 0.f);
    }
    if (act1) {
        float out = W_b[a1];
        #pragma unroll 4
        for (int c = 0; c < A_; ++c) out += axs[r1][c] * W_w[a1 * A_ + c];
        xout[((size_t)b * L_ + row0 + r1) * A_ + a1] = fmaxf(out, 0.f);
    }
}

// ---------------- K5: rank-1 extras for layer 2: Vv (B,L), T,S (B,A); zero pooled
__global__ __launch_bounds__(256) void k_extras(
    const float* __restrict__ x1, const float* __restrict__ Wx_w,
    float* __restrict__ Vv, float* __restrict__ T, float* __restrict__ S,
    float* __restrict__ pooled)
{
    __shared__ float b1s[A_], b2s[A_], Ul[L_];
    const int tid = threadIdx.x, b = blockIdx.x;
    if (tid < A_) {
        float s1 = 0.f, s2 = 0.f;
        #pragma unroll
        for (int g = 0; g < H_; ++g) {
            s1 += Wx_w[g * 204 + 4 + tid];
            s2 += Wx_w[g * 204 + 104 + tid];
        }
        b1s[tid] = s1; b2s[tid] = s2;
        pooled[b * A_ + tid] = 0.f;
    }
    __syncthreads();
    for (int j = tid; j < L_; j += 256) {
        const float* xr = x1 + ((size_t)b * L_ + j) * A_;
        float u = 0.f, v = 0.f;
        #pragma unroll 4
        for (int c = 0; c < A_; ++c) { float xv = xr[c]; u += xv * b1s[c]; v += xv * b2s[c]; }
        Ul[j] = u;
        Vv[b * L_ + j] = v;
    }
    __syncthreads();
    if (tid < A_) {
        float t = 0.f, s = 0.f;
        for (int j = 0; j < L_; ++j) {
            float xv = x1[((size_t)b * L_ + j) * A_ + tid];
            t += xv; s += Ul[j] * xv;
        }
        T[b * A_ + tid] = t; S[b * A_ + tid] = s;
    }
}

// ---------------- K6: node = relu([x,x1,x2]@agg^T + b); pooled += node (atomic)
__global__ __launch_bounds__(128) void k_node(
    const float* __restrict__ x, const float* __restrict__ x1, const float* __restrict__ x2,
    const float* __restrict__ agg_w, const float* __restrict__ agg_b,
    float* __restrict__ pooled)
{
    __shared__ float fs[3 * A_];
    const int tid = threadIdx.x, r = blockIdx.x, b = r >> 9;
    if (tid < A_) {
        fs[tid]          = x[(size_t)r * A_ + tid];
        fs[A_ + tid]     = x1[(size_t)r * A_ + tid];
        fs[2 * A_ + tid] = x2[(size_t)r * A_ + tid];
    }
    __syncthreads();
    if (tid < A_) {
        float acc = agg_b[tid];
        const float* wr = agg_w + (size_t)tid * (3 * A_);
        #pragma unroll 4
        for (int c = 0; c < 3 * A_; ++c) acc += fs[c] * wr[c];
        atomicAdd(&pooled[b * A_ + tid], fmaxf(acc, 0.f));
    }
}

// ---------------- K7: logits = (pooled/valid_len) @ cls^T + b
__global__ __launch_bounds__(64) void k_logits(
    const float* __restrict__ pooled, const float* __restrict__ cls_w,
    const float* __restrict__ cls_b, const int* __restrict__ mask_ids,
    float* __restrict__ out)
{
    const int tid = threadIdx.x;
    if (tid < B_ * P_) {
        const int b = tid / P_, p = tid % P_;
        int vs = 0;
        for (int l = 0; l < L_; ++l) vs += mask_ids[b * L_ + l];
        float inv = 1.0f / (float)max(vs, 1);
        float acc = cls_b[p];
        #pragma unroll 4
        for (int a = 0; a < A_; ++a) acc += (pooled[b * A_ + a] * inv) * cls_w[p * A_ + a];
        out[b * P_ + p] = acc;
    }
}

extern "C" void kernel_launch(void* const* d_in, const int* in_sizes, int n_in,
                              void* d_out, int out_size, void* d_ws, size_t ws_size,
                              hipStream_t stream) {
    const float* seq    = (const float*)d_in[0];
    const float* syn    = (const float*)d_in[1];
    const float* ln_a   = (const float*)d_in[2];
    const float* ln_b   = (const float*)d_in[3];
    const float* Wxx_w  = (const float*)d_in[4];
    const float* Wxx_b  = (const float*)d_in[5];
    const float* q_w    = (const float*)d_in[6];
    const float* q_b    = (const float*)d_in[7];
    const float* k_w    = (const float*)d_in[8];
    const float* k_b    = (const float*)d_in[9];
    const float* W_w    = (const float*)d_in[10];
    const float* W_b    = (const float*)d_in[11];
    const float* Wx_w   = (const float*)d_in[12];
    const float* Wx_b   = (const float*)d_in[13];
    const float* agg_w  = (const float*)d_in[14];
    const float* agg_b  = (const float*)d_in[15];
    const float* cls_w  = (const float*)d_in[16];
    const float* cls_b  = (const float*)d_in[17];
    const int* mask_ids = (const int*)d_in[18];
    const int* src_mask = (const int*)d_in[19];
    float* out = (float*)d_out;

    float* ws = (float*)d_ws;
    size_t off = 0;
    float* x      = ws + off; off += (size_t)B_ * L_ * A_;
    float* x1     = ws + off; off += (size_t)B_ * L_ * A_;
    float* x2     = ws + off; off += (size_t)B_ * L_ * A_;
    float* qt     = ws + off; off += (size_t)B_ * L_ * A_;
    float* kt     = ws + off; off += (size_t)B_ * L_ * A_;
    float* adjsum = ws + off; off += (size_t)B_ * L_ * L_;
    float* wadj   = ws + off; off += (size_t)B_ * L_ * L_;
    float* Vv     = ws + off; off += (size_t)B_ * L_;
    float* T      = ws + off; off += (size_t)B_ * A_;
    float* S      = ws + off; off += (size_t)B_ * A_;
    float* pooled = ws + off; off += (size_t)B_ * A_;
    float* wT     = ws + off; off += (size_t)D_ * 128;

    k_wprep<<<(D_ * 128) / 256, 256, 0, stream>>>(Wxx_w, wT);
    k_lnx<<<(B_ * L_) / 32, 256, 0, stream>>>(seq, ln_a, ln_b, wT, Wxx_b, x);
    k_qk<<<B_ * L_, 256, 0, stream>>>(x, q_w, q_b, k_w, k_b, qt, kt);
    k_scores<<<B_ * L_, 256, 0, stream>>>(qt, kt, syn, src_mask, Wx_w, adjsum, wadj);
    k_ax<0><<<dim3(L_ / ROWS, B_), 256, 0, stream>>>(adjsum, x, W_w, W_b,
                                                     nullptr, nullptr, nullptr, nullptr, x1);
    k_extras<<<B_, 256, 0, stream>>>(x1, Wx_w, Vv, T, S, pooled);
    k_ax<1><<<dim3(L_ / ROWS, B_), 256, 0, stream>>>(wadj, x1, W_w, W_b, S, T, Vv, Wx_b, x2);
    k_node<<<B_ * L_, 128, 0, stream>>>(x, x1, x2, agg_w, agg_b, pooled);
    k_logits<<<1, 64, 0, stream>>>(pooled, cls_w, cls_b, mask_ids, out);
}

// Round 3
// 695.137 us; speedup vs baseline: 1.5484x; 1.2000x over previous
//
#include <hip/hip_runtime.h>

#define B_ 16
#define L_ 512
#define D_ 768
#define H_ 4
#define A_ 100
#define DK_ 25
#define P_ 3

// ------------------------------------------------- K0: wT[d][a] = Wxx_w[a][d], pad a to 128
__global__ __launch_bounds__(256) void k_wprep(const float* __restrict__ Wxx_w,
                                               float* __restrict__ wT)
{
    const int idx = blockIdx.x * 256 + threadIdx.x;     // 768*128
    const int d = idx >> 7, a = idx & 127;
    wT[idx] = (a < A_) ? Wxx_w[(size_t)a * D_ + d] : 0.f;
}

// ------------------- K1: fused LayerNorm + x = seq_ln @ Wxx^T + b  (tiled GEMM)
__global__ __launch_bounds__(256) void k_lnx(
    const float* __restrict__ seq, const float* __restrict__ ln_a, const float* __restrict__ ln_b,
    const float* __restrict__ wT, const float* __restrict__ Wxx_b, float* __restrict__ x)
{
    __shared__ float ss[32][36];
    __shared__ float ws[32][128];
    __shared__ float mean_s[32], rd_s[32];
    const int tid = threadIdx.x;
    const int row0 = blockIdx.x * 32;
    const int wv = tid >> 6, lane = tid & 63;

    for (int rr = 0; rr < 8; ++rr) {
        const int r = wv * 8 + rr;
        const float4* src = (const float4*)(seq + (size_t)(row0 + r) * D_);
        float4 a = src[lane], b = src[lane + 64], c = src[lane + 128];
        float s = a.x + a.y + a.z + a.w + b.x + b.y + b.z + b.w + c.x + c.y + c.z + c.w;
        #pragma unroll
        for (int o = 32; o; o >>= 1) s += __shfl_xor(s, o);
        const float m = s * (1.0f / 768.0f);
        float q = (a.x-m)*(a.x-m) + (a.y-m)*(a.y-m) + (a.z-m)*(a.z-m) + (a.w-m)*(a.w-m)
                + (b.x-m)*(b.x-m) + (b.y-m)*(b.y-m) + (b.z-m)*(b.z-m) + (b.w-m)*(b.w-m)
                + (c.x-m)*(c.x-m) + (c.y-m)*(c.y-m) + (c.z-m)*(c.z-m) + (c.w-m)*(c.w-m);
        #pragma unroll
        for (int o = 32; o; o >>= 1) q += __shfl_xor(q, o);
        if (lane == 0) {
            mean_s[r] = m;
            rd_s[r] = 1.0f / (sqrtf(q * (1.0f / 767.0f)) + 1e-6f);
        }
    }
    __syncthreads();

    const int c4 = tid & 31, rg = tid >> 5;
    float4 acc[4];
    #pragma unroll
    for (int i = 0; i < 4; ++i) { acc[i].x = acc[i].y = acc[i].z = acc[i].w = 0.f; }

    for (int kc = 0; kc < 24; ++kc) {
        {
            const int r = tid >> 3, k4 = tid & 7;
            float4 v = *(const float4*)(seq + (size_t)(row0 + r) * D_ + kc * 32 + k4 * 4);
            float4 la = ((const float4*)ln_a)[kc * 8 + k4];
            float4 lb = ((const float4*)ln_b)[kc * 8 + k4];
            const float m = mean_s[r], rd = rd_s[r];
            float4 o;
            o.x = la.x * ((v.x - m) * rd) + lb.x;
            o.y = la.y * ((v.y - m) * rd) + lb.y;
            o.z = la.z * ((v.z - m) * rd) + lb.z;
            o.w = la.w * ((v.w - m) * rd) + lb.w;
            *(float4*)&ss[r][k4 * 4] = o;
        }
        #pragma unroll
        for (int t = 0; t < 4; ++t) {
            const int idx = tid + t * 256;
            const int k = idx >> 5, cc = idx & 31;
            *(float4*)&ws[k][cc * 4] = *(const float4*)(wT + (size_t)(kc * 32 + k) * 128 + cc * 4);
        }
        __syncthreads();
        #pragma unroll 2
        for (int k = 0; k < 32; k += 4) {
            float4 sv[4];
            #pragma unroll
            for (int i = 0; i < 4; ++i) sv[i] = *(float4*)&ss[rg * 4 + i][k];
            #pragma unroll
            for (int j = 0; j < 4; ++j) {
                float4 w4 = *(float4*)&ws[k + j][c4 * 4];
                #pragma unroll
                for (int i = 0; i < 4; ++i) {
                    const float sj = ((float*)&sv[i])[j];
                    acc[i].x += sj * w4.x; acc[i].y += sj * w4.y;
                    acc[i].z += sj * w4.z; acc[i].w += sj * w4.w;
                }
            }
        }
        __syncthreads();
    }

    if (c4 < 25) {
        const float4 bias = ((const float4*)Wxx_b)[c4];
        #pragma unroll
        for (int i = 0; i < 4; ++i) {
            float4 o;
            o.x = acc[i].x + bias.x; o.y = acc[i].y + bias.y;
            o.z = acc[i].z + bias.z; o.w = acc[i].w + bias.w;
            *(float4*)(x + (size_t)(row0 + rg * 4 + i) * A_ + c4 * 4) = o;
        }
    }
}

// ------------------------------------------------- K2: q/k projections -> (B,H,L,DK)
__global__ __launch_bounds__(256) void k_qk(
    const float* __restrict__ x, const float* __restrict__ q_w, const float* __restrict__ q_b,
    const float* __restrict__ k_w, const float* __restrict__ k_b,
    float* __restrict__ qt, float* __restrict__ kt)
{
    __shared__ float xs[A_];
    const int tid = threadIdx.x, r = blockIdx.x;
    const int b = r >> 9, l = r & 511;
    if (tid < A_) xs[tid] = x[(size_t)r * A_ + tid];
    __syncthreads();
    if (tid < 2 * A_) {
        const int m = tid / A_, a = tid % A_;
        const float* w = m ? k_w : q_w;
        float acc = m ? k_b[a] : q_b[a];
        #pragma unroll 4
        for (int c = 0; c < A_; ++c) acc += xs[c] * w[a * A_ + c];
        const int h = a / DK_, dk = a % DK_;
        float* dst = m ? kt : qt;
        dst[(((size_t)b * H_ + h) * L_ + l) * DK_ + dk] = acc;
    }
}

// --------------- K3a: es[bh][i][j] = (mask? q.k/5 : -1e9) + syn   (64x64 tile GEMM, K=25)
__global__ __launch_bounds__(256) void k_sgemm(
    const float* __restrict__ qt, const float* __restrict__ kt,
    const float* __restrict__ syn, const int* __restrict__ src_mask,
    float* __restrict__ es)
{
    __shared__ float qs[DK_][64];
    __shared__ float ks[DK_][64];
    __shared__ int ms[64];
    const int tid = threadIdx.x;
    const int bh = blockIdx.z;
    const int b = bh >> 2;
    const int i0 = blockIdx.x * 64, j0 = blockIdx.y * 64;
    const float* qbase = qt + ((size_t)bh * L_ + i0) * DK_;
    const float* kbase = kt + ((size_t)bh * L_ + j0) * DK_;
    {
        const int r = tid >> 2, c = tid & 3;
        #pragma unroll
        for (int k = 0; k < 7; ++k) {
            const int d = c + 4 * k;
            if (d < DK_) {
                qs[d][r] = qbase[r * DK_ + d];
                ks[d][r] = kbase[r * DK_ + d];
            }
        }
        if (tid < 64) ms[tid] = src_mask[b * L_ + j0 + tid];
    }
    __syncthreads();
    const int ty = tid >> 4, tx = tid & 15;
    float acc[4][4] = {};
    #pragma unroll 5
    for (int d = 0; d < DK_; ++d) {
        float4 qv = *(const float4*)&qs[d][ty * 4];
        float4 kv = *(const float4*)&ks[d][tx * 4];
        const float q[4] = {qv.x, qv.y, qv.z, qv.w};
        const float kk[4] = {kv.x, kv.y, kv.z, kv.w};
        #pragma unroll
        for (int ii = 0; ii < 4; ++ii)
            #pragma unroll
            for (int jj = 0; jj < 4; ++jj)
                acc[ii][jj] += q[ii] * kk[jj];
    }
    const int irow = i0 + ty * 4, jcol = j0 + tx * 4;
    const int m0 = ms[tx * 4], m1 = ms[tx * 4 + 1], m2 = ms[tx * 4 + 2], m3 = ms[tx * 4 + 3];
    #pragma unroll
    for (int ii = 0; ii < 4; ++ii) {
        const size_t o = ((size_t)bh * L_ + irow + ii) * L_ + jcol;
        float4 sv = *(const float4*)(syn + o);
        float4 w;
        w.x = (m0 ? acc[ii][0] * 0.2f : -1e9f) + sv.x;
        w.y = (m1 ? acc[ii][1] * 0.2f : -1e9f) + sv.y;
        w.z = (m2 ? acc[ii][2] * 0.2f : -1e9f) + sv.z;
        w.w = (m3 ? acc[ii][3] * 0.2f : -1e9f) + sv.w;
        *(float4*)(es + o) = w;
    }
}

// --------------- K3b: softmax over j per (b,h,i); writes adjsum -> es plane0, wadj -> plane1
__global__ __launch_bounds__(256) void k_softmax(
    const float* __restrict__ Wx_w, float* __restrict__ es)
{
    __shared__ float ps[H_][L_];
    __shared__ float cs[H_];
    const int tid = threadIdx.x, r = blockIdx.x;
    const int b = r >> 9, i = r & 511;
    const int h = tid >> 6, lane = tid & 63;
    if (tid < H_) cs[tid] = Wx_w[tid] + Wx_w[204 + tid] + Wx_w[408 + tid] + Wx_w[612 + tid];
    float* row = es + (((size_t)(b * H_ + h)) * L_ + i) * L_;
    float4 v0 = ((const float4*)row)[lane];
    float4 v1 = ((const float4*)row)[lane + 64];
    float mx = fmaxf(fmaxf(fmaxf(v0.x, v0.y), fmaxf(v0.z, v0.w)),
                     fmaxf(fmaxf(v1.x, v1.y), fmaxf(v1.z, v1.w)));
    #pragma unroll
    for (int o = 32; o; o >>= 1) mx = fmaxf(mx, __shfl_xor(mx, o));
    float4 e0, e1;
    e0.x = __expf(v0.x - mx); e0.y = __expf(v0.y - mx);
    e0.z = __expf(v0.z - mx); e0.w = __expf(v0.w - mx);
    e1.x = __expf(v1.x - mx); e1.y = __expf(v1.y - mx);
    e1.z = __expf(v1.z - mx); e1.w = __expf(v1.w - mx);
    float sum = e0.x + e0.y + e0.z + e0.w + e1.x + e1.y + e1.z + e1.w;
    #pragma unroll
    for (int o = 32; o; o >>= 1) sum += __shfl_xor(sum, o);
    const float inv = 1.0f / sum;
    e0.x *= inv; e0.y *= inv; e0.z *= inv; e0.w *= inv;
    e1.x *= inv; e1.y *= inv; e1.z *= inv; e1.w *= inv;
    *(float4*)&ps[h][lane * 4] = e0;
    *(float4*)&ps[h][(lane + 64) * 4] = e1;
    __syncthreads();
    float* arow = es + (((size_t)(b * H_ + 0)) * L_ + i) * L_;
    float* wrow = es + (((size_t)(b * H_ + 1)) * L_ + i) * L_;
    const int t = tid & 127;
    float4 p0 = *(float4*)&ps[0][t * 4];
    float4 p1 = *(float4*)&ps[1][t * 4];
    float4 p2 = *(float4*)&ps[2][t * 4];
    float4 p3 = *(float4*)&ps[3][t * 4];
    if (tid < 128) {
        float4 o;
        o.x = p0.x + p1.x + p2.x + p3.x;
        o.y = p0.y + p1.y + p2.y + p3.y;
        o.z = p0.z + p1.z + p2.z + p3.z;
        o.w = p0.w + p1.w + p2.w + p3.w;
        *(float4*)(arow + t * 4) = o;
    } else {
        const float c0 = cs[0], c1 = cs[1], c2 = cs[2], c3 = cs[3];
        float4 o;
        o.x = c0 * p0.x + c1 * p1.x + c2 * p2.x + c3 * p3.x;
        o.y = c0 * p0.y + c1 * p1.y + c2 * p2.y + c3 * p3.y;
        o.z = c0 * p0.z + c1 * p1.z + c2 * p2.z + c3 * p3.z;
        o.w = c0 * p0.w + c1 * p1.w + c2 * p2.w + c3 * p3.w;
        *(float4*)(wrow + t * 4) = o;
    }
}

// ------------- K4: x_out = relu(((adj@xin)/H [+extras]) @ W^T + b), 4 rows per block
// adj has batch stride 4*L*L (es planes); base pointer pre-offset to the right plane.
#define ROWS 4
template<int LAYER2>
__global__ __launch_bounds__(256) void k_ax(
    const float* __restrict__ adj, const float* __restrict__ xin,
    const float* __restrict__ W_w, const float* __restrict__ W_b,
    const float* __restrict__ S, const float* __restrict__ T,
    const float* __restrict__ Vv, const float* __restrict__ Wx_b,
    float* __restrict__ xout)
{
    __shared__ float xs[64][A_];
    __shared__ float adjs[ROWS][64];
    __shared__ float axs[ROWS][A_];
    const int tid = threadIdx.x;
    const int b = blockIdx.y, row0 = blockIdx.x * ROWS;
    const float* adjb = adj + (size_t)b * 4 * L_ * L_;
    const int o0 = tid;
    const int r0 = o0 / A_, a0 = o0 % A_;
    const int o1 = tid + 256;
    const bool act1 = (o1 < ROWS * A_);
    const int r1 = act1 ? o1 / A_ : 0, a1 = act1 ? o1 % A_ : 0;
    float acc0 = 0.f, acc1 = 0.f;

    for (int kc = 0; kc < L_ / 64; ++kc) {
        for (int idx = tid; idx < 64 * (A_ / 4); idx += 256) {
            int kr = idx / (A_ / 4), c4 = idx % (A_ / 4);
            ((float4*)&xs[kr][0])[c4] =
                ((const float4*)(xin + ((size_t)b * L_ + kc * 64 + kr) * A_))[c4];
        }
        {
            int ar = tid >> 6, ak = tid & 63;
            adjs[ar][ak] = adjb[(size_t)(row0 + ar) * L_ + kc * 64 + ak];
        }
        __syncthreads();
        #pragma unroll 8
        for (int k = 0; k < 64; ++k) {
            acc0 += adjs[r0][k] * xs[k][a0];
            acc1 += adjs[r1][k] * xs[k][a1];
        }
        __syncthreads();
    }

    float wb = 0.f;
    if (LAYER2) wb = Wx_b[0] + Wx_b[1] + Wx_b[2] + Wx_b[3];
    {
        float ax = acc0;
        if (LAYER2) ax += S[b * A_ + a0] + (Vv[b * L_ + row0 + r0] + wb) * T[b * A_ + a0];
        axs[r0][a0] = ax * 0.25f;
    }
    if (act1) {
        float ax = acc1;
        if (LAYER2) ax += S[b * A_ + a1] + (Vv[b * L_ + row0 + r1] + wb) * T[b * A_ + a1];
        axs[r1][a1] = ax * 0.25f;
    }
    __syncthreads();
    {
        float out = W_b[a0];
        #pragma unroll 4
        for (int c = 0; c < A_; ++c) out += axs[r0][c] * W_w[a0 * A_ + c];
        xout[((size_t)b * L_ + row0 + r0) * A_ + a0] = fmaxf(out, 0.f);
    }
    if (act1) {
        float out = W_b[a1];
        #pragma unroll 4
        for (int c = 0; c < A_; ++c) out += axs[r1][c] * W_w[a1 * A_ + c];
        xout[((size_t)b * L_ + row0 + r1) * A_ + a1] = fmaxf(out, 0.f);
    }
}

// ---------------- K5: rank-1 extras for layer 2: Vv (B,L), T,S (B,A); zero pooled
__global__ __launch_bounds__(256) void k_extras(
    const float* __restrict__ x1, const float* __restrict__ Wx_w,
    float* __restrict__ Vv, float* __restrict__ T, float* __restrict__ S,
    float* __restrict__ pooled)
{
    __shared__ float b1s[A_], b2s[A_], Ul[L_];
    const int tid = threadIdx.x, b = blockIdx.x;
    if (tid < A_) {
        float s1 = 0.f, s2 = 0.f;
        #pragma unroll
        for (int g = 0; g < H_; ++g) {
            s1 += Wx_w[g * 204 + 4 + tid];
            s2 += Wx_w[g * 204 + 104 + tid];
        }
        b1s[tid] = s1; b2s[tid] = s2;
        pooled[b * A_ + tid] = 0.f;
    }
    __syncthreads();
    for (int j = tid; j < L_; j += 256) {
        const float* xr = x1 + ((size_t)b * L_ + j) * A_;
        float u = 0.f, v = 0.f;
        #pragma unroll 4
        for (int c = 0; c < A_; ++c) { float xv = xr[c]; u += xv * b1s[c]; v += xv * b2s[c]; }
        Ul[j] = u;
        Vv[b * L_ + j] = v;
    }
    __syncthreads();
    if (tid < A_) {
        float t = 0.f, s = 0.f;
        for (int j = 0; j < L_; ++j) {
            float xv = x1[((size_t)b * L_ + j) * A_ + tid];
            t += xv; s += Ul[j] * xv;
        }
        T[b * A_ + tid] = t; S[b * A_ + tid] = s;
    }
}

// ---------------- K6: node = relu([x,x1,x2]@agg^T + b); pooled += node (atomic)
__global__ __launch_bounds__(128) void k_node(
    const float* __restrict__ x, const float* __restrict__ x1, const float* __restrict__ x2,
    const float* __restrict__ agg_w, const float* __restrict__ agg_b,
    float* __restrict__ pooled)
{
    __shared__ float fs[3 * A_];
    const int tid = threadIdx.x, r = blockIdx.x, b = r >> 9;
    if (tid < A_) {
        fs[tid]          = x[(size_t)r * A_ + tid];
        fs[A_ + tid]     = x1[(size_t)r * A_ + tid];
        fs[2 * A_ + tid] = x2[(size_t)r * A_ + tid];
    }
    __syncthreads();
    if (tid < A_) {
        float acc = agg_b[tid];
        const float* wr = agg_w + (size_t)tid * (3 * A_);
        #pragma unroll 4
        for (int c = 0; c < 3 * A_; ++c) acc += fs[c] * wr[c];
        atomicAdd(&pooled[b * A_ + tid], fmaxf(acc, 0.f));
    }
}

// ---------------- K7: logits = (pooled/valid_len) @ cls^T + b
__global__ __launch_bounds__(64) void k_logits(
    const float* __restrict__ pooled, const float* __restrict__ cls_w,
    const float* __restrict__ cls_b, const int* __restrict__ mask_ids,
    float* __restrict__ out)
{
    const int tid = threadIdx.x;
    if (tid < B_ * P_) {
        const int b = tid / P_, p = tid % P_;
        int vs = 0;
        for (int l = 0; l < L_; ++l) vs += mask_ids[b * L_ + l];
        float inv = 1.0f / (float)max(vs, 1);
        float acc = cls_b[p];
        #pragma unroll 4
        for (int a = 0; a < A_; ++a) acc += (pooled[b * A_ + a] * inv) * cls_w[p * A_ + a];
        out[b * P_ + p] = acc;
    }
}

extern "C" void kernel_launch(void* const* d_in, const int* in_sizes, int n_in,
                              void* d_out, int out_size, void* d_ws, size_t ws_size,
                              hipStream_t stream) {
    const float* seq    = (const float*)d_in[0];
    const float* syn    = (const float*)d_in[1];
    const float* ln_a   = (const float*)d_in[2];
    const float* ln_b   = (const float*)d_in[3];
    const float* Wxx_w  = (const float*)d_in[4];
    const float* Wxx_b  = (const float*)d_in[5];
    const float* q_w    = (const float*)d_in[6];
    const float* q_b    = (const float*)d_in[7];
    const float* k_w    = (const float*)d_in[8];
    const float* k_b    = (const float*)d_in[9];
    const float* W_w    = (const float*)d_in[10];
    const float* W_b    = (const float*)d_in[11];
    const float* Wx_w   = (const float*)d_in[12];
    const float* Wx_b   = (const float*)d_in[13];
    const float* agg_w  = (const float*)d_in[14];
    const float* agg_b  = (const float*)d_in[15];
    const float* cls_w  = (const float*)d_in[16];
    const float* cls_b  = (const float*)d_in[17];
    const int* mask_ids = (const int*)d_in[18];
    const int* src_mask = (const int*)d_in[19];
    float* out = (float*)d_out;

    float* ws = (float*)d_ws;
    size_t off = 0;
    float* x      = ws + off; off += (size_t)B_ * L_ * A_;
    float* x1     = ws + off; off += (size_t)B_ * L_ * A_;
    float* x2     = ws + off; off += (size_t)B_ * L_ * A_;
    float* qt     = ws + off; off += (size_t)B_ * L_ * A_;
    float* kt     = ws + off; off += (size_t)B_ * L_ * A_;
    float* es     = ws + off; off += (size_t)B_ * H_ * L_ * L_;
    float* Vv     = ws + off; off += (size_t)B_ * L_;
    float* T      = ws + off; off += (size_t)B_ * A_;
    float* S      = ws + off; off += (size_t)B_ * A_;
    float* pooled = ws + off; off += (size_t)B_ * A_;
    float* wT     = ws + off; off += (size_t)D_ * 128;

    k_wprep<<<(D_ * 128) / 256, 256, 0, stream>>>(Wxx_w, wT);
    k_lnx<<<(B_ * L_) / 32, 256, 0, stream>>>(seq, ln_a, ln_b, wT, Wxx_b, x);
    k_qk<<<B_ * L_, 256, 0, stream>>>(x, q_w, q_b, k_w, k_b, qt, kt);
    k_sgemm<<<dim3(8, 8, B_ * H_), 256, 0, stream>>>(qt, kt, syn, src_mask, es);
    k_softmax<<<B_ * L_, 256, 0, stream>>>(Wx_w, es);
    k_ax<0><<<dim3(L_ / ROWS, B_), 256, 0, stream>>>(es, x, W_w, W_b,
                                                     nullptr, nullptr, nullptr, nullptr, x1);
    k_extras<<<B_, 256, 0, stream>>>(x1, Wx_w, Vv, T, S, pooled);
    k_ax<1><<<dim3(L_ / ROWS, B_), 256, 0, stream>>>(es + (size_t)L_ * L_, x1, W_w, W_b,
                                                     S, T, Vv, Wx_b, x2);
    k_node<<<B_ * L_, 128, 0, stream>>>(x, x1, x2, agg_w, agg_b, pooled);
    k_logits<<<1, 64, 0, stream>>>(pooled, cls_w, cls_b, mask_ids, out);
}

// Round 4
// 612.437 us; speedup vs baseline: 1.7574x; 1.1350x over previous
//
#include <hip/hip_runtime.h>

#define B_ 16
#define L_ 512
#define D_ 768
#define H_ 4
#define A_ 100
#define DK_ 25
#define P_ 3

// ------------------------------------------------- K0: wT[d][a] = Wxx_w[a][d], pad a to 128
__global__ __launch_bounds__(256) void k_wprep(const float* __restrict__ Wxx_w,
                                               float* __restrict__ wT)
{
    const int idx = blockIdx.x * 256 + threadIdx.x;     // 768*128
    const int d = idx >> 7, a = idx & 127;
    wT[idx] = (a < A_) ? Wxx_w[(size_t)a * D_ + d] : 0.f;
}

// ------------------------------------- K0b: aggT[c][k][n] = agg_w[n][c*100+k], pad n to 128
__global__ __launch_bounds__(256) void k_aggprep(const float* __restrict__ agg_w,
                                                 float* __restrict__ aggT)
{
    const int idx = blockIdx.x * 256 + threadIdx.x;     // 3*100*128 = 38400
    const int n = idx & 127, k = (idx >> 7) % A_, c = idx / (128 * A_);
    aggT[idx] = (n < A_) ? agg_w[(size_t)n * (3 * A_) + c * A_ + k] : 0.f;
}

// ------------------- K1: fused LayerNorm + x = seq_ln @ Wxx^T + b  (tiled GEMM)
__global__ __launch_bounds__(256) void k_lnx(
    const float* __restrict__ seq, const float* __restrict__ ln_a, const float* __restrict__ ln_b,
    const float* __restrict__ wT, const float* __restrict__ Wxx_b, float* __restrict__ x)
{
    __shared__ float ss[32][36];
    __shared__ float ws[32][128];
    __shared__ float mean_s[32], rd_s[32];
    const int tid = threadIdx.x;
    const int row0 = blockIdx.x * 32;
    const int wv = tid >> 6, lane = tid & 63;

    for (int rr = 0; rr < 8; ++rr) {
        const int r = wv * 8 + rr;
        const float4* src = (const float4*)(seq + (size_t)(row0 + r) * D_);
        float4 a = src[lane], b = src[lane + 64], c = src[lane + 128];
        float s = a.x + a.y + a.z + a.w + b.x + b.y + b.z + b.w + c.x + c.y + c.z + c.w;
        #pragma unroll
        for (int o = 32; o; o >>= 1) s += __shfl_xor(s, o);
        const float m = s * (1.0f / 768.0f);
        float q = (a.x-m)*(a.x-m) + (a.y-m)*(a.y-m) + (a.z-m)*(a.z-m) + (a.w-m)*(a.w-m)
                + (b.x-m)*(b.x-m) + (b.y-m)*(b.y-m) + (b.z-m)*(b.z-m) + (b.w-m)*(b.w-m)
                + (c.x-m)*(c.x-m) + (c.y-m)*(c.y-m) + (c.z-m)*(c.z-m) + (c.w-m)*(c.w-m);
        #pragma unroll
        for (int o = 32; o; o >>= 1) q += __shfl_xor(q, o);
        if (lane == 0) {
            mean_s[r] = m;
            rd_s[r] = 1.0f / (sqrtf(q * (1.0f / 767.0f)) + 1e-6f);
        }
    }
    __syncthreads();

    const int c4 = tid & 31, rg = tid >> 5;
    float4 acc[4];
    #pragma unroll
    for (int i = 0; i < 4; ++i) { acc[i].x = acc[i].y = acc[i].z = acc[i].w = 0.f; }

    for (int kc = 0; kc < 24; ++kc) {
        {
            const int r = tid >> 3, k4 = tid & 7;
            float4 v = *(const float4*)(seq + (size_t)(row0 + r) * D_ + kc * 32 + k4 * 4);
            float4 la = ((const float4*)ln_a)[kc * 8 + k4];
            float4 lb = ((const float4*)ln_b)[kc * 8 + k4];
            const float m = mean_s[r], rd = rd_s[r];
            float4 o;
            o.x = la.x * ((v.x - m) * rd) + lb.x;
            o.y = la.y * ((v.y - m) * rd) + lb.y;
            o.z = la.z * ((v.z - m) * rd) + lb.z;
            o.w = la.w * ((v.w - m) * rd) + lb.w;
            *(float4*)&ss[r][k4 * 4] = o;
        }
        #pragma unroll
        for (int t = 0; t < 4; ++t) {
            const int idx = tid + t * 256;
            const int k = idx >> 5, cc = idx & 31;
            *(float4*)&ws[k][cc * 4] = *(const float4*)(wT + (size_t)(kc * 32 + k) * 128 + cc * 4);
        }
        __syncthreads();
        #pragma unroll 2
        for (int k = 0; k < 32; k += 4) {
            float4 sv[4];
            #pragma unroll
            for (int i = 0; i < 4; ++i) sv[i] = *(float4*)&ss[rg * 4 + i][k];
            #pragma unroll
            for (int j = 0; j < 4; ++j) {
                float4 w4 = *(float4*)&ws[k + j][c4 * 4];
                #pragma unroll
                for (int i = 0; i < 4; ++i) {
                    const float sj = ((float*)&sv[i])[j];
                    acc[i].x += sj * w4.x; acc[i].y += sj * w4.y;
                    acc[i].z += sj * w4.z; acc[i].w += sj * w4.w;
                }
            }
        }
        __syncthreads();
    }

    if (c4 < 25) {
        const float4 bias = ((const float4*)Wxx_b)[c4];
        #pragma unroll
        for (int i = 0; i < 4; ++i) {
            float4 o;
            o.x = acc[i].x + bias.x; o.y = acc[i].y + bias.y;
            o.z = acc[i].z + bias.z; o.w = acc[i].w + bias.w;
            *(float4*)(x + (size_t)(row0 + rg * 4 + i) * A_ + c4 * 4) = o;
        }
    }
}

// ------------------------------------------------- K2: q/k projections -> (B,H,L,DK)
__global__ __launch_bounds__(256) void k_qk(
    const float* __restrict__ x, const float* __restrict__ q_w, const float* __restrict__ q_b,
    const float* __restrict__ k_w, const float* __restrict__ k_b,
    float* __restrict__ qt, float* __restrict__ kt)
{
    __shared__ float xs[A_];
    const int tid = threadIdx.x, r = blockIdx.x;
    const int b = r >> 9, l = r & 511;
    if (tid < A_) xs[tid] = x[(size_t)r * A_ + tid];
    __syncthreads();
    if (tid < 2 * A_) {
        const int m = tid / A_, a = tid % A_;
        const float* w = m ? k_w : q_w;
        float acc = m ? k_b[a] : q_b[a];
        #pragma unroll 4
        for (int c = 0; c < A_; ++c) acc += xs[c] * w[a * A_ + c];
        const int h = a / DK_, dk = a % DK_;
        float* dst = m ? kt : qt;
        dst[(((size_t)b * H_ + h) * L_ + l) * DK_ + dk] = acc;
    }
}

// --------------- K3a: es[bh][i][j] = (mask? q.k/5 : -1e9) + syn   (64x64 tile GEMM, K=25)
__global__ __launch_bounds__(256) void k_sgemm(
    const float* __restrict__ qt, const float* __restrict__ kt,
    const float* __restrict__ syn, const int* __restrict__ src_mask,
    float* __restrict__ es)
{
    __shared__ float qs[DK_][64];
    __shared__ float ks[DK_][64];
    __shared__ int ms[64];
    const int tid = threadIdx.x;
    const int bh = blockIdx.z;
    const int b = bh >> 2;
    const int i0 = blockIdx.x * 64, j0 = blockIdx.y * 64;
    const float* qbase = qt + ((size_t)bh * L_ + i0) * DK_;
    const float* kbase = kt + ((size_t)bh * L_ + j0) * DK_;
    {
        const int r = tid >> 2, c = tid & 3;
        #pragma unroll
        for (int k = 0; k < 7; ++k) {
            const int d = c + 4 * k;
            if (d < DK_) {
                qs[d][r] = qbase[r * DK_ + d];
                ks[d][r] = kbase[r * DK_ + d];
            }
        }
        if (tid < 64) ms[tid] = src_mask[b * L_ + j0 + tid];
    }
    __syncthreads();
    const int ty = tid >> 4, tx = tid & 15;
    float acc[4][4] = {};
    #pragma unroll 5
    for (int d = 0; d < DK_; ++d) {
        float4 qv = *(const float4*)&qs[d][ty * 4];
        float4 kv = *(const float4*)&ks[d][tx * 4];
        const float q[4] = {qv.x, qv.y, qv.z, qv.w};
        const float kk[4] = {kv.x, kv.y, kv.z, kv.w};
        #pragma unroll
        for (int ii = 0; ii < 4; ++ii)
            #pragma unroll
            for (int jj = 0; jj < 4; ++jj)
                acc[ii][jj] += q[ii] * kk[jj];
    }
    const int irow = i0 + ty * 4, jcol = j0 + tx * 4;
    const int m0 = ms[tx * 4], m1 = ms[tx * 4 + 1], m2 = ms[tx * 4 + 2], m3 = ms[tx * 4 + 3];
    #pragma unroll
    for (int ii = 0; ii < 4; ++ii) {
        const size_t o = ((size_t)bh * L_ + irow + ii) * L_ + jcol;
        float4 sv = *(const float4*)(syn + o);
        float4 w;
        w.x = (m0 ? acc[ii][0] * 0.2f : -1e9f) + sv.x;
        w.y = (m1 ? acc[ii][1] * 0.2f : -1e9f) + sv.y;
        w.z = (m2 ? acc[ii][2] * 0.2f : -1e9f) + sv.z;
        w.w = (m3 ? acc[ii][3] * 0.2f : -1e9f) + sv.w;
        *(float4*)(es + o) = w;
    }
}

// --------------- K3b: softmax over j per (b,h,i); writes adjsum -> es plane0, wadj -> plane1
__global__ __launch_bounds__(256) void k_softmax(
    const float* __restrict__ Wx_w, float* __restrict__ es)
{
    __shared__ float ps[H_][L_];
    __shared__ float cs[H_];
    const int tid = threadIdx.x, r = blockIdx.x;
    const int b = r >> 9, i = r & 511;
    const int h = tid >> 6, lane = tid & 63;
    if (tid < H_) cs[tid] = Wx_w[tid] + Wx_w[204 + tid] + Wx_w[408 + tid] + Wx_w[612 + tid];
    float* row = es + (((size_t)(b * H_ + h)) * L_ + i) * L_;
    float4 v0 = ((const float4*)row)[lane];
    float4 v1 = ((const float4*)row)[lane + 64];
    float mx = fmaxf(fmaxf(fmaxf(v0.x, v0.y), fmaxf(v0.z, v0.w)),
                     fmaxf(fmaxf(v1.x, v1.y), fmaxf(v1.z, v1.w)));
    #pragma unroll
    for (int o = 32; o; o >>= 1) mx = fmaxf(mx, __shfl_xor(mx, o));
    float4 e0, e1;
    e0.x = __expf(v0.x - mx); e0.y = __expf(v0.y - mx);
    e0.z = __expf(v0.z - mx); e0.w = __expf(v0.w - mx);
    e1.x = __expf(v1.x - mx); e1.y = __expf(v1.y - mx);
    e1.z = __expf(v1.z - mx); e1.w = __expf(v1.w - mx);
    float sum = e0.x + e0.y + e0.z + e0.w + e1.x + e1.y + e1.z + e1.w;
    #pragma unroll
    for (int o = 32; o; o >>= 1) sum += __shfl_xor(sum, o);
    const float inv = 1.0f / sum;
    e0.x *= inv; e0.y *= inv; e0.z *= inv; e0.w *= inv;
    e1.x *= inv; e1.y *= inv; e1.z *= inv; e1.w *= inv;
    *(float4*)&ps[h][lane * 4] = e0;
    *(float4*)&ps[h][(lane + 64) * 4] = e1;
    __syncthreads();
    float* arow = es + (((size_t)(b * H_ + 0)) * L_ + i) * L_;
    float* wrow = es + (((size_t)(b * H_ + 1)) * L_ + i) * L_;
    const int t = tid & 127;
    float4 p0 = *(float4*)&ps[0][t * 4];
    float4 p1 = *(float4*)&ps[1][t * 4];
    float4 p2 = *(float4*)&ps[2][t * 4];
    float4 p3 = *(float4*)&ps[3][t * 4];
    if (tid < 128) {
        float4 o;
        o.x = p0.x + p1.x + p2.x + p3.x;
        o.y = p0.y + p1.y + p2.y + p3.y;
        o.z = p0.z + p1.z + p2.z + p3.z;
        o.w = p0.w + p1.w + p2.w + p3.w;
        *(float4*)(arow + t * 4) = o;
    } else {
        const float c0 = cs[0], c1 = cs[1], c2 = cs[2], c3 = cs[3];
        float4 o;
        o.x = c0 * p0.x + c1 * p1.x + c2 * p2.x + c3 * p3.x;
        o.y = c0 * p0.y + c1 * p1.y + c2 * p2.y + c3 * p3.y;
        o.z = c0 * p0.z + c1 * p1.z + c2 * p2.z + c3 * p3.z;
        o.w = c0 * p0.w + c1 * p1.w + c2 * p2.w + c3 * p3.w;
        *(float4*)(wrow + t * 4) = o;
    }
}

// ------------- K4: x_out = relu(((adj@xin)/H [+extras]) @ W^T + b), 4 rows per block
#define ROWS 4
template<int LAYER2>
__global__ __launch_bounds__(256) void k_ax(
    const float* __restrict__ adj, const float* __restrict__ xin,
    const float* __restrict__ W_w, const float* __restrict__ W_b,
    const float* __restrict__ S, const float* __restrict__ T,
    const float* __restrict__ Vv, const float* __restrict__ Wx_b,
    float* __restrict__ xout)
{
    __shared__ float xs[64][A_];
    __shared__ float adjs[ROWS][64];
    __shared__ float axs[ROWS][A_];
    const int tid = threadIdx.x;
    const int b = blockIdx.y, row0 = blockIdx.x * ROWS;
    const float* adjb = adj + (size_t)b * 4 * L_ * L_;
    const int o0 = tid;
    const int r0 = o0 / A_, a0 = o0 % A_;
    const int o1 = tid + 256;
    const bool act1 = (o1 < ROWS * A_);
    const int r1 = act1 ? o1 / A_ : 0, a1 = act1 ? o1 % A_ : 0;
    float acc0 = 0.f, acc1 = 0.f;

    for (int kc = 0; kc < L_ / 64; ++kc) {
        for (int idx = tid; idx < 64 * (A_ / 4); idx += 256) {
            int kr = idx / (A_ / 4), c4 = idx % (A_ / 4);
            ((float4*)&xs[kr][0])[c4] =
                ((const float4*)(xin + ((size_t)b * L_ + kc * 64 + kr) * A_))[c4];
        }
        {
            int ar = tid >> 6, ak = tid & 63;
            adjs[ar][ak] = adjb[(size_t)(row0 + ar) * L_ + kc * 64 + ak];
        }
        __syncthreads();
        #pragma unroll 8
        for (int k = 0; k < 64; ++k) {
            acc0 += adjs[r0][k] * xs[k][a0];
            acc1 += adjs[r1][k] * xs[k][a1];
        }
        __syncthreads();
    }

    float wb = 0.f;
    if (LAYER2) wb = Wx_b[0] + Wx_b[1] + Wx_b[2] + Wx_b[3];
    {
        float ax = acc0;
        if (LAYER2) ax += S[b * A_ + a0] + (Vv[b * L_ + row0 + r0] + wb) * T[b * A_ + a0];
        axs[r0][a0] = ax * 0.25f;
    }
    if (act1) {
        float ax = acc1;
        if (LAYER2) ax += S[b * A_ + a1] + (Vv[b * L_ + row0 + r1] + wb) * T[b * A_ + a1];
        axs[r1][a1] = ax * 0.25f;
    }
    __syncthreads();
    {
        float out = W_b[a0];
        #pragma unroll 4
        for (int c = 0; c < A_; ++c) out += axs[r0][c] * W_w[a0 * A_ + c];
        xout[((size_t)b * L_ + row0 + r0) * A_ + a0] = fmaxf(out, 0.f);
    }
    if (act1) {
        float out = W_b[a1];
        #pragma unroll 4
        for (int c = 0; c < A_; ++c) out += axs[r1][c] * W_w[a1 * A_ + c];
        xout[((size_t)b * L_ + row0 + r1) * A_ + a1] = fmaxf(out, 0.f);
    }
}

// ---------------- K5: rank-1 extras for layer 2: Vv (B,L), T,S (B,A); zero pooled
__global__ __launch_bounds__(256) void k_extras(
    const float* __restrict__ x1, const float* __restrict__ Wx_w,
    float* __restrict__ Vv, float* __restrict__ T, float* __restrict__ S,
    float* __restrict__ pooled)
{
    __shared__ float b1s[A_], b2s[A_], Ul[L_];
    const int tid = threadIdx.x, b = blockIdx.x;
    if (tid < A_) {
        float s1 = 0.f, s2 = 0.f;
        #pragma unroll
        for (int g = 0; g < H_; ++g) {
            s1 += Wx_w[g * 204 + 4 + tid];
            s2 += Wx_w[g * 204 + 104 + tid];
        }
        b1s[tid] = s1; b2s[tid] = s2;
        pooled[b * A_ + tid] = 0.f;
    }
    __syncthreads();
    for (int j = tid; j < L_; j += 256) {
        const float* xr = x1 + ((size_t)b * L_ + j) * A_;
        float u = 0.f, v = 0.f;
        #pragma unroll 4
        for (int c = 0; c < A_; ++c) { float xv = xr[c]; u += xv * b1s[c]; v += xv * b2s[c]; }
        Ul[j] = u;
        Vv[b * L_ + j] = v;
    }
    __syncthreads();
    if (tid < A_) {
        float t = 0.f, s = 0.f;
        for (int j = 0; j < L_; ++j) {
            float xv = x1[((size_t)b * L_ + j) * A_ + tid];
            t += xv; s += Ul[j] * xv;
        }
        T[b * A_ + tid] = t; S[b * A_ + tid] = s;
    }
}

// ---------------- K6: pooled[b] += sum_rows relu([x,x1,x2]@agg^T + b)   (tiled GEMM)
// block: 32 rows x 128 cols; 3 K-chunks of 100 (x, x1, x2). node never hits global.
__global__ __launch_bounds__(256) void k_nodepool(
    const float* __restrict__ x, const float* __restrict__ x1, const float* __restrict__ x2,
    const float* __restrict__ aggT, const float* __restrict__ agg_b,
    float* __restrict__ pooled)
{
    __shared__ float ss[32][104];       // +4 pad
    __shared__ float ws[A_][128];
    const int tid = threadIdx.x;
    const int row0 = blockIdx.x * 32;   // global row in [0, B*L)
    const int b = row0 >> 9;
    const int c4 = tid & 31, rg = tid >> 5;
    float4 acc[4];
    #pragma unroll
    for (int i = 0; i < 4; ++i) { acc[i].x = acc[i].y = acc[i].z = acc[i].w = 0.f; }

    for (int c = 0; c < 3; ++c) {
        const float* src = (c == 0) ? x : (c == 1) ? x1 : x2;
        for (int idx = tid; idx < 32 * 25; idx += 256) {
            const int r = idx / 25, k4 = idx % 25;
            *(float4*)&ss[r][k4 * 4] =
                *(const float4*)(src + (size_t)(row0 + r) * A_ + k4 * 4);
        }
        for (int idx = tid; idx < A_ * 32; idx += 256) {
            const int k = idx >> 5, cc = idx & 31;
            *(float4*)&ws[k][cc * 4] =
                *(const float4*)(aggT + ((size_t)c * A_ + k) * 128 + cc * 4);
        }
        __syncthreads();
        #pragma unroll 5
        for (int k = 0; k < A_; k += 4) {
            float4 sv[4];
            #pragma unroll
            for (int i = 0; i < 4; ++i) sv[i] = *(float4*)&ss[rg * 4 + i][k];
            #pragma unroll
            for (int j = 0; j < 4; ++j) {
                float4 w4 = *(float4*)&ws[k + j][c4 * 4];
                #pragma unroll
                for (int i = 0; i < 4; ++i) {
                    const float sj = ((float*)&sv[i])[j];
                    acc[i].x += sj * w4.x; acc[i].y += sj * w4.y;
                    acc[i].z += sj * w4.z; acc[i].w += sj * w4.w;
                }
            }
        }
        __syncthreads();
    }

    // bias + relu + per-thread row-group sum
    float4 bias = {0.f, 0.f, 0.f, 0.f};
    if (c4 < 25) bias = ((const float4*)agg_b)[c4];
    float4 rs = {0.f, 0.f, 0.f, 0.f};
    #pragma unroll
    for (int i = 0; i < 4; ++i) {
        rs.x += fmaxf(acc[i].x + bias.x, 0.f);
        rs.y += fmaxf(acc[i].y + bias.y, 0.f);
        rs.z += fmaxf(acc[i].z + bias.z, 0.f);
        rs.w += fmaxf(acc[i].w + bias.w, 0.f);
    }
    // cross-row-group reduce in LDS (reuse ss), then atomics into pooled
    float* red = &ss[0][0];             // [8][128]
    __syncthreads();
    *(float4*)&red[rg * 128 + c4 * 4] = rs;
    __syncthreads();
    if (rg == 0 && c4 < 25) {
        float4 tot = {0.f, 0.f, 0.f, 0.f};
        #pragma unroll
        for (int g = 0; g < 8; ++g) {
            float4 v = *(float4*)&red[g * 128 + c4 * 4];
            tot.x += v.x; tot.y += v.y; tot.z += v.z; tot.w += v.w;
        }
        atomicAdd(&pooled[b * A_ + c4 * 4 + 0], tot.x);
        atomicAdd(&pooled[b * A_ + c4 * 4 + 1], tot.y);
        atomicAdd(&pooled[b * A_ + c4 * 4 + 2], tot.z);
        atomicAdd(&pooled[b * A_ + c4 * 4 + 3], tot.w);
    }
}

// ---------------- K7: logits = (pooled/valid_len) @ cls^T + b
__global__ __launch_bounds__(64) void k_logits(
    const float* __restrict__ pooled, const float* __restrict__ cls_w,
    const float* __restrict__ cls_b, const int* __restrict__ mask_ids,
    float* __restrict__ out)
{
    const int tid = threadIdx.x;
    if (tid < B_ * P_) {
        const int b = tid / P_, p = tid % P_;
        int vs = 0;
        for (int l = 0; l < L_; ++l) vs += mask_ids[b * L_ + l];
        float inv = 1.0f / (float)max(vs, 1);
        float acc = cls_b[p];
        #pragma unroll 4
        for (int a = 0; a < A_; ++a) acc += (pooled[b * A_ + a] * inv) * cls_w[p * A_ + a];
        out[b * P_ + p] = acc;
    }
}

extern "C" void kernel_launch(void* const* d_in, const int* in_sizes, int n_in,
                              void* d_out, int out_size, void* d_ws, size_t ws_size,
                              hipStream_t stream) {
    const float* seq    = (const float*)d_in[0];
    const float* syn    = (const float*)d_in[1];
    const float* ln_a   = (const float*)d_in[2];
    const float* ln_b   = (const float*)d_in[3];
    const float* Wxx_w  = (const float*)d_in[4];
    const float* Wxx_b  = (const float*)d_in[5];
    const float* q_w    = (const float*)d_in[6];
    const float* q_b    = (const float*)d_in[7];
    const float* k_w    = (const float*)d_in[8];
    const float* k_b    = (const float*)d_in[9];
    const float* W_w    = (const float*)d_in[10];
    const float* W_b    = (const float*)d_in[11];
    const float* Wx_w   = (const float*)d_in[12];
    const float* Wx_b   = (const float*)d_in[13];
    const float* agg_w  = (const float*)d_in[14];
    const float* agg_b  = (const float*)d_in[15];
    const float* cls_w  = (const float*)d_in[16];
    const float* cls_b  = (const float*)d_in[17];
    const int* mask_ids = (const int*)d_in[18];
    const int* src_mask = (const int*)d_in[19];
    float* out = (float*)d_out;

    float* ws = (float*)d_ws;
    size_t off = 0;
    float* x      = ws + off; off += (size_t)B_ * L_ * A_;
    float* x1     = ws + off; off += (size_t)B_ * L_ * A_;
    float* x2     = ws + off; off += (size_t)B_ * L_ * A_;
    float* qt     = ws + off; off += (size_t)B_ * L_ * A_;
    float* kt     = ws + off; off += (size_t)B_ * L_ * A_;
    float* es     = ws + off; off += (size_t)B_ * H_ * L_ * L_;
    float* Vv     = ws + off; off += (size_t)B_ * L_;
    float* T      = ws + off; off += (size_t)B_ * A_;
    float* S      = ws + off; off += (size_t)B_ * A_;
    float* pooled = ws + off; off += (size_t)B_ * A_;
    float* wT     = ws + off; off += (size_t)D_ * 128;
    float* aggT   = ws + off; off += (size_t)3 * A_ * 128;

    k_wprep<<<(D_ * 128) / 256, 256, 0, stream>>>(Wxx_w, wT);
    k_aggprep<<<(3 * A_ * 128) / 256, 256, 0, stream>>>(agg_w, aggT);
    k_lnx<<<(B_ * L_) / 32, 256, 0, stream>>>(seq, ln_a, ln_b, wT, Wxx_b, x);
    k_qk<<<B_ * L_, 256, 0, stream>>>(x, q_w, q_b, k_w, k_b, qt, kt);
    k_sgemm<<<dim3(8, 8, B_ * H_), 256, 0, stream>>>(qt, kt, syn, src_mask, es);
    k_softmax<<<B_ * L_, 256, 0, stream>>>(Wx_w, es);
    k_ax<0><<<dim3(L_ / ROWS, B_), 256, 0, stream>>>(es, x, W_w, W_b,
                                                     nullptr, nullptr, nullptr, nullptr, x1);
    k_extras<<<B_, 256, 0, stream>>>(x1, Wx_w, Vv, T, S, pooled);
    k_ax<1><<<dim3(L_ / ROWS, B_), 256, 0, stream>>>(es + (size_t)L_ * L_, x1, W_w, W_b,
                                                     S, T, Vv, Wx_b, x2);
    k_nodepool<<<(B_ * L_) / 32, 256, 0, stream>>>(x, x1, x2, aggT, agg_b, pooled);
    k_logits<<<1, 64, 0, stream>>>(pooled, cls_w, cls_b, mask_ids, out);
}

// Round 5
// 525.953 us; speedup vs baseline: 2.0464x; 1.1644x over previous
//
#include <hip/hip_runtime.h>

#define B_ 16
#define L_ 512
#define D_ 768
#define H_ 4
#define A_ 100
#define DK_ 25
#define P_ 3

// ------------------------------------------------- K0: wT[d][a] = Wxx_w[a][d], pad a to 128
__global__ __launch_bounds__(256) void k_wprep(const float* __restrict__ Wxx_w,
                                               float* __restrict__ wT)
{
    const int idx = blockIdx.x * 256 + threadIdx.x;     // 768*128
    const int d = idx >> 7, a = idx & 127;
    wT[idx] = (a < A_) ? Wxx_w[(size_t)a * D_ + d] : 0.f;
}

// ------------------------------------- K0b: aggT[c][k][n] = agg_w[n][c*100+k], pad n to 128
__global__ __launch_bounds__(256) void k_aggprep(const float* __restrict__ agg_w,
                                                 float* __restrict__ aggT)
{
    const int idx = blockIdx.x * 256 + threadIdx.x;     // 3*100*128 = 38400
    const int n = idx & 127, k = (idx >> 7) % A_, c = idx / (128 * A_);
    aggT[idx] = (n < A_) ? agg_w[(size_t)n * (3 * A_) + c * A_ + k] : 0.f;
}

// ------------------------------------- K0c: qkT[k][n]: n<128 -> q_w[n][k], n>=128 -> k_w[n-128][k]
__global__ __launch_bounds__(256) void k_qkprep(const float* __restrict__ q_w,
                                                const float* __restrict__ k_w,
                                                float* __restrict__ qkT)
{
    const int idx = blockIdx.x * 256 + threadIdx.x;     // 100*256 = 25600
    const int n = idx & 255, k = idx >> 8;
    const int half = n >> 7, a = n & 127;
    const float* w = half ? k_w : q_w;
    qkT[idx] = (a < A_) ? w[(size_t)a * A_ + k] : 0.f;
}

// ------------------- K1: fused LayerNorm + x = seq_ln @ Wxx^T + b  (tiled GEMM)
__global__ __launch_bounds__(256) void k_lnx(
    const float* __restrict__ seq, const float* __restrict__ ln_a, const float* __restrict__ ln_b,
    const float* __restrict__ wT, const float* __restrict__ Wxx_b, float* __restrict__ x)
{
    __shared__ float ss[32][36];
    __shared__ float ws[32][128];
    __shared__ float mean_s[32], rd_s[32];
    const int tid = threadIdx.x;
    const int row0 = blockIdx.x * 32;
    const int wv = tid >> 6, lane = tid & 63;

    for (int rr = 0; rr < 8; ++rr) {
        const int r = wv * 8 + rr;
        const float4* src = (const float4*)(seq + (size_t)(row0 + r) * D_);
        float4 a = src[lane], b = src[lane + 64], c = src[lane + 128];
        float s = a.x + a.y + a.z + a.w + b.x + b.y + b.z + b.w + c.x + c.y + c.z + c.w;
        #pragma unroll
        for (int o = 32; o; o >>= 1) s += __shfl_xor(s, o);
        const float m = s * (1.0f / 768.0f);
        float q = (a.x-m)*(a.x-m) + (a.y-m)*(a.y-m) + (a.z-m)*(a.z-m) + (a.w-m)*(a.w-m)
                + (b.x-m)*(b.x-m) + (b.y-m)*(b.y-m) + (b.z-m)*(b.z-m) + (b.w-m)*(b.w-m)
                + (c.x-m)*(c.x-m) + (c.y-m)*(c.y-m) + (c.z-m)*(c.z-m) + (c.w-m)*(c.w-m);
        #pragma unroll
        for (int o = 32; o; o >>= 1) q += __shfl_xor(q, o);
        if (lane == 0) {
            mean_s[r] = m;
            rd_s[r] = 1.0f / (sqrtf(q * (1.0f / 767.0f)) + 1e-6f);
        }
    }
    __syncthreads();

    const int c4 = tid & 31, rg = tid >> 5;
    float4 acc[4];
    #pragma unroll
    for (int i = 0; i < 4; ++i) { acc[i].x = acc[i].y = acc[i].z = acc[i].w = 0.f; }

    for (int kc = 0; kc < 24; ++kc) {
        {
            const int r = tid >> 3, k4 = tid & 7;
            float4 v = *(const float4*)(seq + (size_t)(row0 + r) * D_ + kc * 32 + k4 * 4);
            float4 la = ((const float4*)ln_a)[kc * 8 + k4];
            float4 lb = ((const float4*)ln_b)[kc * 8 + k4];
            const float m = mean_s[r], rd = rd_s[r];
            float4 o;
            o.x = la.x * ((v.x - m) * rd) + lb.x;
            o.y = la.y * ((v.y - m) * rd) + lb.y;
            o.z = la.z * ((v.z - m) * rd) + lb.z;
            o.w = la.w * ((v.w - m) * rd) + lb.w;
            *(float4*)&ss[r][k4 * 4] = o;
        }
        #pragma unroll
        for (int t = 0; t < 4; ++t) {
            const int idx = tid + t * 256;
            const int k = idx >> 5, cc = idx & 31;
            *(float4*)&ws[k][cc * 4] = *(const float4*)(wT + (size_t)(kc * 32 + k) * 128 + cc * 4);
        }
        __syncthreads();
        #pragma unroll 2
        for (int k = 0; k < 32; k += 4) {
            float4 sv[4];
            #pragma unroll
            for (int i = 0; i < 4; ++i) sv[i] = *(float4*)&ss[rg * 4 + i][k];
            #pragma unroll
            for (int j = 0; j < 4; ++j) {
                float4 w4 = *(float4*)&ws[k + j][c4 * 4];
                #pragma unroll
                for (int i = 0; i < 4; ++i) {
                    const float sj = ((float*)&sv[i])[j];
                    acc[i].x += sj * w4.x; acc[i].y += sj * w4.y;
                    acc[i].z += sj * w4.z; acc[i].w += sj * w4.w;
                }
            }
        }
        __syncthreads();
    }

    if (c4 < 25) {
        const float4 bias = ((const float4*)Wxx_b)[c4];
        #pragma unroll
        for (int i = 0; i < 4; ++i) {
            float4 o;
            o.x = acc[i].x + bias.x; o.y = acc[i].y + bias.y;
            o.z = acc[i].z + bias.z; o.w = acc[i].w + bias.w;
            *(float4*)(x + (size_t)(row0 + rg * 4 + i) * A_ + c4 * 4) = o;
        }
    }
}

// ------------------- K2: q/k = x @ [q_w|k_w]^T + bias  (tiled GEMM, 32 rows x 128 cols)
// qt/kt stored (B, L, A) row-major.
__global__ __launch_bounds__(256) void k_qkg(
    const float* __restrict__ x, const float* __restrict__ qkT,
    const float* __restrict__ q_b, const float* __restrict__ k_b,
    float* __restrict__ qt, float* __restrict__ kt)
{
    __shared__ float ss[32][104];       // +4 pad
    __shared__ float ws[A_][128];
    const int tid = threadIdx.x;
    const int row0 = blockIdx.x * 32;
    const int half = blockIdx.y;        // 0 = q, 1 = k
    const int c4 = tid & 31, rg = tid >> 5;

    for (int idx = tid; idx < 32 * 25; idx += 256) {
        const int r = idx / 25, k4 = idx % 25;
        *(float4*)&ss[r][k4 * 4] = *(const float4*)(x + (size_t)(row0 + r) * A_ + k4 * 4);
    }
    for (int idx = tid; idx < A_ * 32; idx += 256) {
        const int k = idx >> 5, cc = idx & 31;
        *(float4*)&ws[k][cc * 4] = *(const float4*)(qkT + (size_t)k * 256 + half * 128 + cc * 4);
    }
    __syncthreads();

    float4 acc[4];
    #pragma unroll
    for (int i = 0; i < 4; ++i) { acc[i].x = acc[i].y = acc[i].z = acc[i].w = 0.f; }
    #pragma unroll 5
    for (int k = 0; k < A_; k += 4) {
        float4 sv[4];
        #pragma unroll
        for (int i = 0; i < 4; ++i) sv[i] = *(float4*)&ss[rg * 4 + i][k];
        #pragma unroll
        for (int j = 0; j < 4; ++j) {
            float4 w4 = *(float4*)&ws[k + j][c4 * 4];
            #pragma unroll
            for (int i = 0; i < 4; ++i) {
                const float sj = ((float*)&sv[i])[j];
                acc[i].x += sj * w4.x; acc[i].y += sj * w4.y;
                acc[i].z += sj * w4.z; acc[i].w += sj * w4.w;
            }
        }
    }

    if (c4 < 25) {
        const float4 bias = ((const float4*)(half ? k_b : q_b))[c4];
        float* dst = half ? kt : qt;
        #pragma unroll
        for (int i = 0; i < 4; ++i) {
            float4 o;
            o.x = acc[i].x + bias.x; o.y = acc[i].y + bias.y;
            o.z = acc[i].z + bias.z; o.w = acc[i].w + bias.w;
            *(float4*)(dst + (size_t)(row0 + rg * 4 + i) * A_ + c4 * 4) = o;
        }
    }
}

// --------------- K3a: es[bh][i][j] = (mask? q.k/5 : -1e9) + syn   (64x64 tile GEMM, K=25)
// qt/kt are (B, L, A); head h occupies cols h*25..h*25+24.
__global__ __launch_bounds__(256) void k_sgemm(
    const float* __restrict__ qt, const float* __restrict__ kt,
    const float* __restrict__ syn, const int* __restrict__ src_mask,
    float* __restrict__ es)
{
    __shared__ float qs[DK_][64];
    __shared__ float ks[DK_][64];
    __shared__ int ms[64];
    const int tid = threadIdx.x;
    const int bh = blockIdx.z;
    const int b = bh >> 2, h = bh & 3;
    const int i0 = blockIdx.x * 64, j0 = blockIdx.y * 64;
    const float* qbase = qt + ((size_t)b * L_ + i0) * A_ + h * DK_;
    const float* kbase = kt + ((size_t)b * L_ + j0) * A_ + h * DK_;
    {
        const int r = tid >> 2, c = tid & 3;
        #pragma unroll
        for (int k = 0; k < 7; ++k) {
            const int d = c + 4 * k;
            if (d < DK_) {
                qs[d][r] = qbase[(size_t)r * A_ + d];
                ks[d][r] = kbase[(size_t)r * A_ + d];
            }
        }
        if (tid < 64) ms[tid] = src_mask[b * L_ + j0 + tid];
    }
    __syncthreads();
    const int ty = tid >> 4, tx = tid & 15;
    float acc[4][4] = {};
    #pragma unroll 5
    for (int d = 0; d < DK_; ++d) {
        float4 qv = *(const float4*)&qs[d][ty * 4];
        float4 kv = *(const float4*)&ks[d][tx * 4];
        const float q[4] = {qv.x, qv.y, qv.z, qv.w};
        const float kk[4] = {kv.x, kv.y, kv.z, kv.w};
        #pragma unroll
        for (int ii = 0; ii < 4; ++ii)
            #pragma unroll
            for (int jj = 0; jj < 4; ++jj)
                acc[ii][jj] += q[ii] * kk[jj];
    }
    const int irow = i0 + ty * 4, jcol = j0 + tx * 4;
    const int m0 = ms[tx * 4], m1 = ms[tx * 4 + 1], m2 = ms[tx * 4 + 2], m3 = ms[tx * 4 + 3];
    #pragma unroll
    for (int ii = 0; ii < 4; ++ii) {
        const size_t o = ((size_t)bh * L_ + irow + ii) * L_ + jcol;
        float4 sv = *(const float4*)(syn + o);
        float4 w;
        w.x = (m0 ? acc[ii][0] * 0.2f : -1e9f) + sv.x;
        w.y = (m1 ? acc[ii][1] * 0.2f : -1e9f) + sv.y;
        w.z = (m2 ? acc[ii][2] * 0.2f : -1e9f) + sv.z;
        w.w = (m3 ? acc[ii][3] * 0.2f : -1e9f) + sv.w;
        *(float4*)(es + o) = w;
    }
}

// --------------- K3b: softmax over j per (b,h,i); writes adjsum -> es plane0, wadj -> plane1
__global__ __launch_bounds__(256) void k_softmax(
    const float* __restrict__ Wx_w, float* __restrict__ es)
{
    __shared__ float ps[H_][L_];
    __shared__ float cs[H_];
    const int tid = threadIdx.x, r = blockIdx.x;
    const int b = r >> 9, i = r & 511;
    const int h = tid >> 6, lane = tid & 63;
    if (tid < H_) cs[tid] = Wx_w[tid] + Wx_w[204 + tid] + Wx_w[408 + tid] + Wx_w[612 + tid];
    float* row = es + (((size_t)(b * H_ + h)) * L_ + i) * L_;
    float4 v0 = ((const float4*)row)[lane];
    float4 v1 = ((const float4*)row)[lane + 64];
    float mx = fmaxf(fmaxf(fmaxf(v0.x, v0.y), fmaxf(v0.z, v0.w)),
                     fmaxf(fmaxf(v1.x, v1.y), fmaxf(v1.z, v1.w)));
    #pragma unroll
    for (int o = 32; o; o >>= 1) mx = fmaxf(mx, __shfl_xor(mx, o));
    float4 e0, e1;
    e0.x = __expf(v0.x - mx); e0.y = __expf(v0.y - mx);
    e0.z = __expf(v0.z - mx); e0.w = __expf(v0.w - mx);
    e1.x = __expf(v1.x - mx); e1.y = __expf(v1.y - mx);
    e1.z = __expf(v1.z - mx); e1.w = __expf(v1.w - mx);
    float sum = e0.x + e0.y + e0.z + e0.w + e1.x + e1.y + e1.z + e1.w;
    #pragma unroll
    for (int o = 32; o; o >>= 1) sum += __shfl_xor(sum, o);
    const float inv = 1.0f / sum;
    e0.x *= inv; e0.y *= inv; e0.z *= inv; e0.w *= inv;
    e1.x *= inv; e1.y *= inv; e1.z *= inv; e1.w *= inv;
    *(float4*)&ps[h][lane * 4] = e0;
    *(float4*)&ps[h][(lane + 64) * 4] = e1;
    __syncthreads();
    float* arow = es + (((size_t)(b * H_ + 0)) * L_ + i) * L_;
    float* wrow = es + (((size_t)(b * H_ + 1)) * L_ + i) * L_;
    const int t = tid & 127;
    float4 p0 = *(float4*)&ps[0][t * 4];
    float4 p1 = *(float4*)&ps[1][t * 4];
    float4 p2 = *(float4*)&ps[2][t * 4];
    float4 p3 = *(float4*)&ps[3][t * 4];
    if (tid < 128) {
        float4 o;
        o.x = p0.x + p1.x + p2.x + p3.x;
        o.y = p0.y + p1.y + p2.y + p3.y;
        o.z = p0.z + p1.z + p2.z + p3.z;
        o.w = p0.w + p1.w + p2.w + p3.w;
        *(float4*)(arow + t * 4) = o;
    } else {
        const float c0 = cs[0], c1 = cs[1], c2 = cs[2], c3 = cs[3];
        float4 o;
        o.x = c0 * p0.x + c1 * p1.x + c2 * p2.x + c3 * p3.x;
        o.y = c0 * p0.y + c1 * p1.y + c2 * p2.y + c3 * p3.y;
        o.z = c0 * p0.z + c1 * p1.z + c2 * p2.z + c3 * p3.z;
        o.w = c0 * p0.w + c1 * p1.w + c2 * p2.w + c3 * p3.w;
        *(float4*)(wrow + t * 4) = o;
    }
}

// ------------- K4: x_out = relu(((adj@xin)/H [+extras]) @ W^T + b), 4 rows per block
#define ROWS 4
template<int LAYER2>
__global__ __launch_bounds__(256) void k_ax(
    const float* __restrict__ adj, const float* __restrict__ xin,
    const float* __restrict__ W_w, const float* __restrict__ W_b,
    const float* __restrict__ S, const float* __restrict__ T,
    const float* __restrict__ Vv, const float* __restrict__ Wx_b,
    float* __restrict__ xout)
{
    __shared__ float xs[64][A_];
    __shared__ float adjs[ROWS][64];
    __shared__ float axs[ROWS][A_];
    const int tid = threadIdx.x;
    const int b = blockIdx.y, row0 = blockIdx.x * ROWS;
    const float* adjb = adj + (size_t)b * 4 * L_ * L_;
    const int o0 = tid;
    const int r0 = o0 / A_, a0 = o0 % A_;
    const int o1 = tid + 256;
    const bool act1 = (o1 < ROWS * A_);
    const int r1 = act1 ? o1 / A_ : 0, a1 = act1 ? o1 % A_ : 0;
    float acc0 = 0.f, acc1 = 0.f;

    for (int kc = 0; kc < L_ / 64; ++kc) {
        for (int idx = tid; idx < 64 * (A_ / 4); idx += 256) {
            int kr = idx / (A_ / 4), c4 = idx % (A_ / 4);
            ((float4*)&xs[kr][0])[c4] =
                ((const float4*)(xin + ((size_t)b * L_ + kc * 64 + kr) * A_))[c4];
        }
        {
            int ar = tid >> 6, ak = tid & 63;
            adjs[ar][ak] = adjb[(size_t)(row0 + ar) * L_ + kc * 64 + ak];
        }
        __syncthreads();
        #pragma unroll 8
        for (int k = 0; k < 64; ++k) {
            acc0 += adjs[r0][k] * xs[k][a0];
            acc1 += adjs[r1][k] * xs[k][a1];
        }
        __syncthreads();
    }

    float wb = 0.f;
    if (LAYER2) wb = Wx_b[0] + Wx_b[1] + Wx_b[2] + Wx_b[3];
    {
        float ax = acc0;
        if (LAYER2) ax += S[b * A_ + a0] + (Vv[b * L_ + row0 + r0] + wb) * T[b * A_ + a0];
        axs[r0][a0] = ax * 0.25f;
    }
    if (act1) {
        float ax = acc1;
        if (LAYER2) ax += S[b * A_ + a1] + (Vv[b * L_ + row0 + r1] + wb) * T[b * A_ + a1];
        axs[r1][a1] = ax * 0.25f;
    }
    __syncthreads();
    {
        float out = W_b[a0];
        #pragma unroll 4
        for (int c = 0; c < A_; ++c) out += axs[r0][c] * W_w[a0 * A_ + c];
        xout[((size_t)b * L_ + row0 + r0) * A_ + a0] = fmaxf(out, 0.f);
    }
    if (act1) {
        float out = W_b[a1];
        #pragma unroll 4
        for (int c = 0; c < A_; ++c) out += axs[r1][c] * W_w[a1 * A_ + c];
        xout[((size_t)b * L_ + row0 + r1) * A_ + a1] = fmaxf(out, 0.f);
    }
}

// ---------------- K5: rank-1 extras for layer 2: Vv (B,L), T,S (B,A); zero pooled
__global__ __launch_bounds__(256) void k_extras(
    const float* __restrict__ x1, const float* __restrict__ Wx_w,
    float* __restrict__ Vv, float* __restrict__ T, float* __restrict__ S,
    float* __restrict__ pooled)
{
    __shared__ float b1s[A_], b2s[A_], Ul[L_];
    const int tid = threadIdx.x, b = blockIdx.x;
    if (tid < A_) {
        float s1 = 0.f, s2 = 0.f;
        #pragma unroll
        for (int g = 0; g < H_; ++g) {
            s1 += Wx_w[g * 204 + 4 + tid];
            s2 += Wx_w[g * 204 + 104 + tid];
        }
        b1s[tid] = s1; b2s[tid] = s2;
        pooled[b * A_ + tid] = 0.f;
    }
    __syncthreads();
    for (int j = tid; j < L_; j += 256) {
        const float* xr = x1 + ((size_t)b * L_ + j) * A_;
        float u = 0.f, v = 0.f;
        #pragma unroll 4
        for (int c = 0; c < A_; ++c) { float xv = xr[c]; u += xv * b1s[c]; v += xv * b2s[c]; }
        Ul[j] = u;
        Vv[b * L_ + j] = v;
    }
    __syncthreads();
    if (tid < A_) {
        float t = 0.f, s = 0.f;
        for (int j = 0; j < L_; ++j) {
            float xv = x1[((size_t)b * L_ + j) * A_ + tid];
            t += xv; s += Ul[j] * xv;
        }
        T[b * A_ + tid] = t; S[b * A_ + tid] = s;
    }
}

// ---------------- K6: pooled[b] += sum_rows relu([x,x1,x2]@agg^T + b)   (tiled GEMM)
__global__ __launch_bounds__(256) void k_nodepool(
    const float* __restrict__ x, const float* __restrict__ x1, const float* __restrict__ x2,
    const float* __restrict__ aggT, const float* __restrict__ agg_b,
    float* __restrict__ pooled)
{
    __shared__ float ss[32][104];
    __shared__ float ws[A_][128];
    const int tid = threadIdx.x;
    const int row0 = blockIdx.x * 32;
    const int b = row0 >> 9;
    const int c4 = tid & 31, rg = tid >> 5;
    float4 acc[4];
    #pragma unroll
    for (int i = 0; i < 4; ++i) { acc[i].x = acc[i].y = acc[i].z = acc[i].w = 0.f; }

    for (int c = 0; c < 3; ++c) {
        const float* src = (c == 0) ? x : (c == 1) ? x1 : x2;
        for (int idx = tid; idx < 32 * 25; idx += 256) {
            const int r = idx / 25, k4 = idx % 25;
            *(float4*)&ss[r][k4 * 4] =
                *(const float4*)(src + (size_t)(row0 + r) * A_ + k4 * 4);
        }
        for (int idx = tid; idx < A_ * 32; idx += 256) {
            const int k = idx >> 5, cc = idx & 31;
            *(float4*)&ws[k][cc * 4] =
                *(const float4*)(aggT + ((size_t)c * A_ + k) * 128 + cc * 4);
        }
        __syncthreads();
        #pragma unroll 5
        for (int k = 0; k < A_; k += 4) {
            float4 sv[4];
            #pragma unroll
            for (int i = 0; i < 4; ++i) sv[i] = *(float4*)&ss[rg * 4 + i][k];
            #pragma unroll
            for (int j = 0; j < 4; ++j) {
                float4 w4 = *(float4*)&ws[k + j][c4 * 4];
                #pragma unroll
                for (int i = 0; i < 4; ++i) {
                    const float sj = ((float*)&sv[i])[j];
                    acc[i].x += sj * w4.x; acc[i].y += sj * w4.y;
                    acc[i].z += sj * w4.z; acc[i].w += sj * w4.w;
                }
            }
        }
        __syncthreads();
    }

    float4 bias = {0.f, 0.f, 0.f, 0.f};
    if (c4 < 25) bias = ((const float4*)agg_b)[c4];
    float4 rs = {0.f, 0.f, 0.f, 0.f};
    #pragma unroll
    for (int i = 0; i < 4; ++i) {
        rs.x += fmaxf(acc[i].x + bias.x, 0.f);
        rs.y += fmaxf(acc[i].y + bias.y, 0.f);
        rs.z += fmaxf(acc[i].z + bias.z, 0.f);
        rs.w += fmaxf(acc[i].w + bias.w, 0.f);
    }
    float* red = &ss[0][0];
    __syncthreads();
    *(float4*)&red[rg * 128 + c4 * 4] = rs;
    __syncthreads();
    if (rg == 0 && c4 < 25) {
        float4 tot = {0.f, 0.f, 0.f, 0.f};
        #pragma unroll
        for (int g = 0; g < 8; ++g) {
            float4 v = *(float4*)&red[g * 128 + c4 * 4];
            tot.x += v.x; tot.y += v.y; tot.z += v.z; tot.w += v.w;
        }
        atomicAdd(&pooled[b * A_ + c4 * 4 + 0], tot.x);
        atomicAdd(&pooled[b * A_ + c4 * 4 + 1], tot.y);
        atomicAdd(&pooled[b * A_ + c4 * 4 + 2], tot.z);
        atomicAdd(&pooled[b * A_ + c4 * 4 + 3], tot.w);
    }
}

// ---------------- K7: logits = (pooled/valid_len) @ cls^T + b
__global__ __launch_bounds__(64) void k_logits(
    const float* __restrict__ pooled, const float* __restrict__ cls_w,
    const float* __restrict__ cls_b, const int* __restrict__ mask_ids,
    float* __restrict__ out)
{
    const int tid = threadIdx.x;
    if (tid < B_ * P_) {
        const int b = tid / P_, p = tid % P_;
        int vs = 0;
        for (int l = 0; l < L_; ++l) vs += mask_ids[b * L_ + l];
        float inv = 1.0f / (float)max(vs, 1);
        float acc = cls_b[p];
        #pragma unroll 4
        for (int a = 0; a < A_; ++a) acc += (pooled[b * A_ + a] * inv) * cls_w[p * A_ + a];
        out[b * P_ + p] = acc;
    }
}

extern "C" void kernel_launch(void* const* d_in, const int* in_sizes, int n_in,
                              void* d_out, int out_size, void* d_ws, size_t ws_size,
                              hipStream_t stream) {
    const float* seq    = (const float*)d_in[0];
    const float* syn    = (const float*)d_in[1];
    const float* ln_a   = (const float*)d_in[2];
    const float* ln_b   = (const float*)d_in[3];
    const float* Wxx_w  = (const float*)d_in[4];
    const float* Wxx_b  = (const float*)d_in[5];
    const float* q_w    = (const float*)d_in[6];
    const float* q_b    = (const float*)d_in[7];
    const float* k_w    = (const float*)d_in[8];
    const float* k_b    = (const float*)d_in[9];
    const float* W_w    = (const float*)d_in[10];
    const float* W_b    = (const float*)d_in[11];
    const float* Wx_w   = (const float*)d_in[12];
    const float* Wx_b   = (const float*)d_in[13];
    const float* agg_w  = (const float*)d_in[14];
    const float* agg_b  = (const float*)d_in[15];
    const float* cls_w  = (const float*)d_in[16];
    const float* cls_b  = (const float*)d_in[17];
    const int* mask_ids = (const int*)d_in[18];
    const int* src_mask = (const int*)d_in[19];
    float* out = (float*)d_out;

    float* ws = (float*)d_ws;
    size_t off = 0;
    float* x      = ws + off; off += (size_t)B_ * L_ * A_;
    float* x1     = ws + off; off += (size_t)B_ * L_ * A_;
    float* x2     = ws + off; off += (size_t)B_ * L_ * A_;
    float* qt     = ws + off; off += (size_t)B_ * L_ * A_;
    float* kt     = ws + off; off += (size_t)B_ * L_ * A_;
    float* es     = ws + off; off += (size_t)B_ * H_ * L_ * L_;
    float* Vv     = ws + off; off += (size_t)B_ * L_;
    float* T      = ws + off; off += (size_t)B_ * A_;
    float* S      = ws + off; off += (size_t)B_ * A_;
    float* pooled = ws + off; off += (size_t)B_ * A_;
    float* wT     = ws + off; off += (size_t)D_ * 128;
    float* aggT   = ws + off; off += (size_t)3 * A_ * 128;
    float* qkT    = ws + off; off += (size_t)A_ * 256;

    k_wprep<<<(D_ * 128) / 256, 256, 0, stream>>>(Wxx_w, wT);
    k_aggprep<<<(3 * A_ * 128) / 256, 256, 0, stream>>>(agg_w, aggT);
    k_qkprep<<<(A_ * 256) / 256, 256, 0, stream>>>(q_w, k_w, qkT);
    k_lnx<<<(B_ * L_) / 32, 256, 0, stream>>>(seq, ln_a, ln_b, wT, Wxx_b, x);
    k_qkg<<<dim3((B_ * L_) / 32, 2), 256, 0, stream>>>(x, qkT, q_b, k_b, qt, kt);
    k_sgemm<<<dim3(8, 8, B_ * H_), 256, 0, stream>>>(qt, kt, syn, src_mask, es);
    k_softmax<<<B_ * L_, 256, 0, stream>>>(Wx_w, es);
    k_ax<0><<<dim3(L_ / ROWS, B_), 256, 0, stream>>>(es, x, W_w, W_b,
                                                     nullptr, nullptr, nullptr, nullptr, x1);
    k_extras<<<B_, 256, 0, stream>>>(x1, Wx_w, Vv, T, S, pooled);
    k_ax<1><<<dim3(L_ / ROWS, B_), 256, 0, stream>>>(es + (size_t)L_ * L_, x1, W_w, W_b,
                                                     S, T, Vv, Wx_b, x2);
    k_nodepool<<<(B_ * L_) / 32, 256, 0, stream>>>(x, x1, x2, aggT, agg_b, pooled);
    k_logits<<<1, 64, 0, stream>>>(pooled, cls_w, cls_b, mask_ids, out);
}

// Round 6
// 401.827 us; speedup vs baseline: 2.6786x; 1.3089x over previous
//
#include <hip/hip_runtime.h>

#define B_ 16
#define L_ 512
#define D_ 768
#define H_ 4
#define A_ 100
#define DK_ 25
#define P_ 3
#define XP_ 128   // padded row stride for x/x1/x2/axb

// ------------------------------------------------- K0: wT[d][a] = Wxx_w[a][d], pad a to 128
__global__ __launch_bounds__(256) void k_wprep(const float* __restrict__ Wxx_w,
                                               float* __restrict__ wT)
{
    const int idx = blockIdx.x * 256 + threadIdx.x;     // 768*128
    const int d = idx >> 7, a = idx & 127;
    wT[idx] = (a < A_) ? Wxx_w[(size_t)a * D_ + d] : 0.f;
}

// ------------------------------------- K0b: aggT[c][k][n] = agg_w[n][c*100+k], pad n to 128
__global__ __launch_bounds__(256) void k_aggprep(const float* __restrict__ agg_w,
                                                 float* __restrict__ aggT)
{
    const int idx = blockIdx.x * 256 + threadIdx.x;     // 3*100*128 = 38400
    const int n = idx & 127, k = (idx >> 7) % A_, c = idx / (128 * A_);
    aggT[idx] = (n < A_) ? agg_w[(size_t)n * (3 * A_) + c * A_ + k] : 0.f;
}

// ------------------------------------- K0c: qkT[k][n]: n<128 -> q_w[n][k], n>=128 -> k_w[n-128][k]
__global__ __launch_bounds__(256) void k_qkprep(const float* __restrict__ q_w,
                                                const float* __restrict__ k_w,
                                                float* __restrict__ qkT)
{
    const int idx = blockIdx.x * 256 + threadIdx.x;     // 100*256 = 25600
    const int n = idx & 255, k = idx >> 8;
    const int half = n >> 7, a = n & 127;
    const float* w = half ? k_w : q_w;
    qkT[idx] = (a < A_) ? w[(size_t)a * A_ + k] : 0.f;
}

// ------------------------------------- K0d: WT[k][n] = W_w[n][k], pad n to 128
__global__ __launch_bounds__(256) void k_wprep2(const float* __restrict__ W_w,
                                                float* __restrict__ WT)
{
    const int idx = blockIdx.x * 256 + threadIdx.x;     // 100*128 = 12800
    const int n = idx & 127, k = idx >> 7;
    WT[idx] = (n < A_) ? W_w[(size_t)n * A_ + k] : 0.f;
}

// ------------------- K1: fused LayerNorm + x = seq_ln @ Wxx^T + b  (tiled GEMM)
// output xp: (B*L, 128), cols 100..127 zero.
__global__ __launch_bounds__(256) void k_lnx(
    const float* __restrict__ seq, const float* __restrict__ ln_a, const float* __restrict__ ln_b,
    const float* __restrict__ wT, const float* __restrict__ Wxx_b, float* __restrict__ xp)
{
    __shared__ float ss[32][36];
    __shared__ float ws[32][128];
    __shared__ float mean_s[32], rd_s[32];
    const int tid = threadIdx.x;
    const int row0 = blockIdx.x * 32;
    const int wv = tid >> 6, lane = tid & 63;

    for (int rr = 0; rr < 8; ++rr) {
        const int r = wv * 8 + rr;
        const float4* src = (const float4*)(seq + (size_t)(row0 + r) * D_);
        float4 a = src[lane], b = src[lane + 64], c = src[lane + 128];
        float s = a.x + a.y + a.z + a.w + b.x + b.y + b.z + b.w + c.x + c.y + c.z + c.w;
        #pragma unroll
        for (int o = 32; o; o >>= 1) s += __shfl_xor(s, o);
        const float m = s * (1.0f / 768.0f);
        float q = (a.x-m)*(a.x-m) + (a.y-m)*(a.y-m) + (a.z-m)*(a.z-m) + (a.w-m)*(a.w-m)
                + (b.x-m)*(b.x-m) + (b.y-m)*(b.y-m) + (b.z-m)*(b.z-m) + (b.w-m)*(b.w-m)
                + (c.x-m)*(c.x-m) + (c.y-m)*(c.y-m) + (c.z-m)*(c.z-m) + (c.w-m)*(c.w-m);
        #pragma unroll
        for (int o = 32; o; o >>= 1) q += __shfl_xor(q, o);
        if (lane == 0) {
            mean_s[r] = m;
            rd_s[r] = 1.0f / (sqrtf(q * (1.0f / 767.0f)) + 1e-6f);
        }
    }
    __syncthreads();

    const int c4 = tid & 31, rg = tid >> 5;
    float4 acc[4];
    #pragma unroll
    for (int i = 0; i < 4; ++i) { acc[i].x = acc[i].y = acc[i].z = acc[i].w = 0.f; }

    for (int kc = 0; kc < 24; ++kc) {
        {
            const int r = tid >> 3, k4 = tid & 7;
            float4 v = *(const float4*)(seq + (size_t)(row0 + r) * D_ + kc * 32 + k4 * 4);
            float4 la = ((const float4*)ln_a)[kc * 8 + k4];
            float4 lb = ((const float4*)ln_b)[kc * 8 + k4];
            const float m = mean_s[r], rd = rd_s[r];
            float4 o;
            o.x = la.x * ((v.x - m) * rd) + lb.x;
            o.y = la.y * ((v.y - m) * rd) + lb.y;
            o.z = la.z * ((v.z - m) * rd) + lb.z;
            o.w = la.w * ((v.w - m) * rd) + lb.w;
            *(float4*)&ss[r][k4 * 4] = o;
        }
        #pragma unroll
        for (int t = 0; t < 4; ++t) {
            const int idx = tid + t * 256;
            const int k = idx >> 5, cc = idx & 31;
            *(float4*)&ws[k][cc * 4] = *(const float4*)(wT + (size_t)(kc * 32 + k) * 128 + cc * 4);
        }
        __syncthreads();
        #pragma unroll 2
        for (int k = 0; k < 32; k += 4) {
            float4 sv[4];
            #pragma unroll
            for (int i = 0; i < 4; ++i) sv[i] = *(float4*)&ss[rg * 4 + i][k];
            #pragma unroll
            for (int j = 0; j < 4; ++j) {
                float4 w4 = *(float4*)&ws[k + j][c4 * 4];
                #pragma unroll
                for (int i = 0; i < 4; ++i) {
                    const float sj = ((float*)&sv[i])[j];
                    acc[i].x += sj * w4.x; acc[i].y += sj * w4.y;
                    acc[i].z += sj * w4.z; acc[i].w += sj * w4.w;
                }
            }
        }
        __syncthreads();
    }

    float4 bias = {0.f, 0.f, 0.f, 0.f};
    if (c4 < 25) bias = ((const float4*)Wxx_b)[c4];
    #pragma unroll
    for (int i = 0; i < 4; ++i) {
        float4 o;
        o.x = acc[i].x + bias.x; o.y = acc[i].y + bias.y;
        o.z = acc[i].z + bias.z; o.w = acc[i].w + bias.w;
        *(float4*)(xp + (size_t)(row0 + rg * 4 + i) * XP_ + c4 * 4) = o;   // pad cols stay 0 (wT padded)
    }
}

// ------------------- K2: q/k = x @ [q_w|k_w]^T + bias  (tiled GEMM); qt/kt (B,L,100)
__global__ __launch_bounds__(256) void k_qkg(
    const float* __restrict__ xp, const float* __restrict__ qkT,
    const float* __restrict__ q_b, const float* __restrict__ k_b,
    float* __restrict__ qt, float* __restrict__ kt)
{
    __shared__ float ss[32][104];
    __shared__ float ws[A_][128];
    const int tid = threadIdx.x;
    const int row0 = blockIdx.x * 32;
    const int half = blockIdx.y;
    const int c4 = tid & 31, rg = tid >> 5;

    for (int idx = tid; idx < 32 * 25; idx += 256) {
        const int r = idx / 25, k4 = idx % 25;
        *(float4*)&ss[r][k4 * 4] = *(const float4*)(xp + (size_t)(row0 + r) * XP_ + k4 * 4);
    }
    for (int idx = tid; idx < A_ * 32; idx += 256) {
        const int k = idx >> 5, cc = idx & 31;
        *(float4*)&ws[k][cc * 4] = *(const float4*)(qkT + (size_t)k * 256 + half * 128 + cc * 4);
    }
    __syncthreads();

    float4 acc[4];
    #pragma unroll
    for (int i = 0; i < 4; ++i) { acc[i].x = acc[i].y = acc[i].z = acc[i].w = 0.f; }
    #pragma unroll 5
    for (int k = 0; k < A_; k += 4) {
        float4 sv[4];
        #pragma unroll
        for (int i = 0; i < 4; ++i) sv[i] = *(float4*)&ss[rg * 4 + i][k];
        #pragma unroll
        for (int j = 0; j < 4; ++j) {
            float4 w4 = *(float4*)&ws[k + j][c4 * 4];
            #pragma unroll
            for (int i = 0; i < 4; ++i) {
                const float sj = ((float*)&sv[i])[j];
                acc[i].x += sj * w4.x; acc[i].y += sj * w4.y;
                acc[i].z += sj * w4.z; acc[i].w += sj * w4.w;
            }
        }
    }

    if (c4 < 25) {
        const float4 bias = ((const float4*)(half ? k_b : q_b))[c4];
        float* dst = half ? kt : qt;
        #pragma unroll
        for (int i = 0; i < 4; ++i) {
            float4 o;
            o.x = acc[i].x + bias.x; o.y = acc[i].y + bias.y;
            o.z = acc[i].z + bias.z; o.w = acc[i].w + bias.w;
            *(float4*)(dst + (size_t)(row0 + rg * 4 + i) * A_ + c4 * 4) = o;
        }
    }
}

// --------------- K3a: es[bh][i][j] = (mask? q.k/5 : -1e9) + syn   (64x64 tile GEMM, K=25)
__global__ __launch_bounds__(256) void k_sgemm(
    const float* __restrict__ qt, const float* __restrict__ kt,
    const float* __restrict__ syn, const int* __restrict__ src_mask,
    float* __restrict__ es)
{
    __shared__ float qs[DK_][64];
    __shared__ float ks[DK_][64];
    __shared__ int ms[64];
    const int tid = threadIdx.x;
    const int bh = blockIdx.z;
    const int b = bh >> 2, h = bh & 3;
    const int i0 = blockIdx.x * 64, j0 = blockIdx.y * 64;
    const float* qbase = qt + ((size_t)b * L_ + i0) * A_ + h * DK_;
    const float* kbase = kt + ((size_t)b * L_ + j0) * A_ + h * DK_;
    {
        const int r = tid >> 2, c = tid & 3;
        #pragma unroll
        for (int k = 0; k < 7; ++k) {
            const int d = c + 4 * k;
            if (d < DK_) {
                qs[d][r] = qbase[(size_t)r * A_ + d];
                ks[d][r] = kbase[(size_t)r * A_ + d];
            }
        }
        if (tid < 64) ms[tid] = src_mask[b * L_ + j0 + tid];
    }
    __syncthreads();
    const int ty = tid >> 4, tx = tid & 15;
    float acc[4][4] = {};
    #pragma unroll 5
    for (int d = 0; d < DK_; ++d) {
        float4 qv = *(const float4*)&qs[d][ty * 4];
        float4 kv = *(const float4*)&ks[d][tx * 4];
        const float q[4] = {qv.x, qv.y, qv.z, qv.w};
        const float kk[4] = {kv.x, kv.y, kv.z, kv.w};
        #pragma unroll
        for (int ii = 0; ii < 4; ++ii)
            #pragma unroll
            for (int jj = 0; jj < 4; ++jj)
                acc[ii][jj] += q[ii] * kk[jj];
    }
    const int irow = i0 + ty * 4, jcol = j0 + tx * 4;
    const int m0 = ms[tx * 4], m1 = ms[tx * 4 + 1], m2 = ms[tx * 4 + 2], m3 = ms[tx * 4 + 3];
    #pragma unroll
    for (int ii = 0; ii < 4; ++ii) {
        const size_t o = ((size_t)bh * L_ + irow + ii) * L_ + jcol;
        float4 sv = *(const float4*)(syn + o);
        float4 w;
        w.x = (m0 ? acc[ii][0] * 0.2f : -1e9f) + sv.x;
        w.y = (m1 ? acc[ii][1] * 0.2f : -1e9f) + sv.y;
        w.z = (m2 ? acc[ii][2] * 0.2f : -1e9f) + sv.z;
        w.w = (m3 ? acc[ii][3] * 0.2f : -1e9f) + sv.w;
        *(float4*)(es + o) = w;
    }
}

// --------------- K3b: softmax over j per (b,h,i); adjsum -> es plane0, wadj -> plane1
__global__ __launch_bounds__(256) void k_softmax(
    const float* __restrict__ Wx_w, float* __restrict__ es)
{
    __shared__ float ps[H_][L_];
    __shared__ float cs[H_];
    const int tid = threadIdx.x, r = blockIdx.x;
    const int b = r >> 9, i = r & 511;
    const int h = tid >> 6, lane = tid & 63;
    if (tid < H_) cs[tid] = Wx_w[tid] + Wx_w[204 + tid] + Wx_w[408 + tid] + Wx_w[612 + tid];
    float* row = es + (((size_t)(b * H_ + h)) * L_ + i) * L_;
    float4 v0 = ((const float4*)row)[lane];
    float4 v1 = ((const float4*)row)[lane + 64];
    float mx = fmaxf(fmaxf(fmaxf(v0.x, v0.y), fmaxf(v0.z, v0.w)),
                     fmaxf(fmaxf(v1.x, v1.y), fmaxf(v1.z, v1.w)));
    #pragma unroll
    for (int o = 32; o; o >>= 1) mx = fmaxf(mx, __shfl_xor(mx, o));
    float4 e0, e1;
    e0.x = __expf(v0.x - mx); e0.y = __expf(v0.y - mx);
    e0.z = __expf(v0.z - mx); e0.w = __expf(v0.w - mx);
    e1.x = __expf(v1.x - mx); e1.y = __expf(v1.y - mx);
    e1.z = __expf(v1.z - mx); e1.w = __expf(v1.w - mx);
    float sum = e0.x + e0.y + e0.z + e0.w + e1.x + e1.y + e1.z + e1.w;
    #pragma unroll
    for (int o = 32; o; o >>= 1) sum += __shfl_xor(sum, o);
    const float inv = 1.0f / sum;
    e0.x *= inv; e0.y *= inv; e0.z *= inv; e0.w *= inv;
    e1.x *= inv; e1.y *= inv; e1.z *= inv; e1.w *= inv;
    *(float4*)&ps[h][lane * 4] = e0;
    *(float4*)&ps[h][(lane + 64) * 4] = e1;
    __syncthreads();
    float* arow = es + (((size_t)(b * H_ + 0)) * L_ + i) * L_;
    float* wrow = es + (((size_t)(b * H_ + 1)) * L_ + i) * L_;
    const int t = tid & 127;
    float4 p0 = *(float4*)&ps[0][t * 4];
    float4 p1 = *(float4*)&ps[1][t * 4];
    float4 p2 = *(float4*)&ps[2][t * 4];
    float4 p3 = *(float4*)&ps[3][t * 4];
    if (tid < 128) {
        float4 o;
        o.x = p0.x + p1.x + p2.x + p3.x;
        o.y = p0.y + p1.y + p2.y + p3.y;
        o.z = p0.z + p1.z + p2.z + p3.z;
        o.w = p0.w + p1.w + p2.w + p3.w;
        *(float4*)(arow + t * 4) = o;
    } else {
        const float c0 = cs[0], c1 = cs[1], c2 = cs[2], c3 = cs[3];
        float4 o;
        o.x = c0 * p0.x + c1 * p1.x + c2 * p2.x + c3 * p3.x;
        o.y = c0 * p0.y + c1 * p1.y + c2 * p2.y + c3 * p3.y;
        o.z = c0 * p0.z + c1 * p1.z + c2 * p2.z + c3 * p3.z;
        o.w = c0 * p0.w + c1 * p1.w + c2 * p2.w + c3 * p3.w;
        *(float4*)(wrow + t * 4) = o;
    }
}

// ------------- K4a: axb = (adj @ x)/H [+ extras]   (tiled GEMM, 32 rows x 128 cols, K=512)
template<int LAYER2>
__global__ __launch_bounds__(256) void k_axg(
    const float* __restrict__ adj, const float* __restrict__ xp,
    const float* __restrict__ S, const float* __restrict__ T,
    const float* __restrict__ Vv, const float* __restrict__ Wx_b,
    float* __restrict__ axb)
{
    __shared__ float ss[32][36];
    __shared__ float ws[32][128];
    const int tid = threadIdx.x;
    const int row0 = blockIdx.x * 32;       // global row in [0, B*L)
    const int b = row0 >> 9, i0 = row0 & 511;
    const float* adjb = adj + (size_t)b * 4 * L_ * L_;
    const int c4 = tid & 31, rg = tid >> 5;
    float4 acc[4];
    #pragma unroll
    for (int i = 0; i < 4; ++i) { acc[i].x = acc[i].y = acc[i].z = acc[i].w = 0.f; }

    for (int kc = 0; kc < 16; ++kc) {
        {
            const int r = tid >> 3, q4 = tid & 7;
            *(float4*)&ss[r][q4 * 4] =
                *(const float4*)(adjb + (size_t)(i0 + r) * L_ + kc * 32 + q4 * 4);
        }
        #pragma unroll
        for (int t = 0; t < 4; ++t) {
            const int idx = tid + t * 256;
            const int k = idx >> 5, cc = idx & 31;
            *(float4*)&ws[k][cc * 4] =
                *(const float4*)(xp + ((size_t)b * L_ + kc * 32 + k) * XP_ + cc * 4);
        }
        __syncthreads();
        #pragma unroll 2
        for (int k = 0; k < 32; k += 4) {
            float4 sv[4];
            #pragma unroll
            for (int i = 0; i < 4; ++i) sv[i] = *(float4*)&ss[rg * 4 + i][k];
            #pragma unroll
            for (int j = 0; j < 4; ++j) {
                float4 w4 = *(float4*)&ws[k + j][c4 * 4];
                #pragma unroll
                for (int i = 0; i < 4; ++i) {
                    const float sj = ((float*)&sv[i])[j];
                    acc[i].x += sj * w4.x; acc[i].y += sj * w4.y;
                    acc[i].z += sj * w4.z; acc[i].w += sj * w4.w;
                }
            }
        }
        __syncthreads();
    }

    float wb = 0.f;
    float4 Sv = {0.f, 0.f, 0.f, 0.f}, Tv = {0.f, 0.f, 0.f, 0.f};
    if (LAYER2) {
        wb = Wx_b[0] + Wx_b[1] + Wx_b[2] + Wx_b[3];
        if (c4 < 25) {
            Sv = ((const float4*)(S + b * A_))[c4];
            Tv = ((const float4*)(T + b * A_))[c4];
        }
    }
    #pragma unroll
    for (int i = 0; i < 4; ++i) {
        const int grow = row0 + rg * 4 + i;
        const float vv = LAYER2 ? (Vv[grow] + wb) : 0.f;
        float4 o;
        o.x = (acc[i].x + Sv.x + vv * Tv.x) * 0.25f;
        o.y = (acc[i].y + Sv.y + vv * Tv.y) * 0.25f;
        o.z = (acc[i].z + Sv.z + vv * Tv.z) * 0.25f;
        o.w = (acc[i].w + Sv.w + vv * Tv.w) * 0.25f;
        *(float4*)(axb + (size_t)grow * XP_ + c4 * 4) = o;   // pad cols -> 0
    }
}

// ------------- K4b: xout = relu(axb @ W^T + b)   (tiled GEMM, K=100)
__global__ __launch_bounds__(256) void k_xw(
    const float* __restrict__ axb, const float* __restrict__ WT,
    const float* __restrict__ W_b, float* __restrict__ xout)
{
    __shared__ float ss[32][104];
    __shared__ float ws[A_][128];
    const int tid = threadIdx.x;
    const int row0 = blockIdx.x * 32;
    const int c4 = tid & 31, rg = tid >> 5;

    for (int idx = tid; idx < 32 * 25; idx += 256) {
        const int r = idx / 25, k4 = idx % 25;
        *(float4*)&ss[r][k4 * 4] = *(const float4*)(axb + (size_t)(row0 + r) * XP_ + k4 * 4);
    }
    for (int idx = tid; idx < A_ * 32; idx += 256) {
        const int k = idx >> 5, cc = idx & 31;
        *(float4*)&ws[k][cc * 4] = *(const float4*)(WT + (size_t)k * 128 + cc * 4);
    }
    __syncthreads();

    float4 acc[4];
    #pragma unroll
    for (int i = 0; i < 4; ++i) { acc[i].x = acc[i].y = acc[i].z = acc[i].w = 0.f; }
    #pragma unroll 5
    for (int k = 0; k < A_; k += 4) {
        float4 sv[4];
        #pragma unroll
        for (int i = 0; i < 4; ++i) sv[i] = *(float4*)&ss[rg * 4 + i][k];
        #pragma unroll
        for (int j = 0; j < 4; ++j) {
            float4 w4 = *(float4*)&ws[k + j][c4 * 4];
            #pragma unroll
            for (int i = 0; i < 4; ++i) {
                const float sj = ((float*)&sv[i])[j];
                acc[i].x += sj * w4.x; acc[i].y += sj * w4.y;
                acc[i].z += sj * w4.z; acc[i].w += sj * w4.w;
            }
        }
    }

    float4 bias = {0.f, 0.f, 0.f, 0.f};
    if (c4 < 25) bias = ((const float4*)W_b)[c4];
    #pragma unroll
    for (int i = 0; i < 4; ++i) {
        float4 o;
        o.x = fmaxf(acc[i].x + bias.x, 0.f); o.y = fmaxf(acc[i].y + bias.y, 0.f);
        o.z = fmaxf(acc[i].z + bias.z, 0.f); o.w = fmaxf(acc[i].w + bias.w, 0.f);
        *(float4*)(xout + (size_t)(row0 + rg * 4 + i) * XP_ + c4 * 4) = o;  // WT pad -> 0
    }
}

// ---------------- K5: rank-1 extras for layer 2: Vv (B,L), T,S (B,A); zero pooled
__global__ __launch_bounds__(256) void k_extras(
    const float* __restrict__ x1, const float* __restrict__ Wx_w,
    float* __restrict__ Vv, float* __restrict__ T, float* __restrict__ S,
    float* __restrict__ pooled)
{
    __shared__ float b1s[A_], b2s[A_], Ul[L_];
    const int tid = threadIdx.x, b = blockIdx.x;
    if (tid < A_) {
        float s1 = 0.f, s2 = 0.f;
        #pragma unroll
        for (int g = 0; g < H_; ++g) {
            s1 += Wx_w[g * 204 + 4 + tid];
            s2 += Wx_w[g * 204 + 104 + tid];
        }
        b1s[tid] = s1; b2s[tid] = s2;
        pooled[b * A_ + tid] = 0.f;
    }
    __syncthreads();
    for (int j = tid; j < L_; j += 256) {
        const float* xr = x1 + ((size_t)b * L_ + j) * XP_;
        float u = 0.f, v = 0.f;
        #pragma unroll 4
        for (int c = 0; c < A_; ++c) { float xv = xr[c]; u += xv * b1s[c]; v += xv * b2s[c]; }
        Ul[j] = u;
        Vv[b * L_ + j] = v;
    }
    __syncthreads();
    if (tid < A_) {
        float t = 0.f, s = 0.f;
        for (int j = 0; j < L_; ++j) {
            float xv = x1[((size_t)b * L_ + j) * XP_ + tid];
            t += xv; s += Ul[j] * xv;
        }
        T[b * A_ + tid] = t; S[b * A_ + tid] = s;
    }
}

// ---------------- K6: pooled[b] += sum_rows relu([x,x1,x2]@agg^T + b)   (tiled GEMM)
__global__ __launch_bounds__(256) void k_nodepool(
    const float* __restrict__ x, const float* __restrict__ x1, const float* __restrict__ x2,
    const float* __restrict__ aggT, const float* __restrict__ agg_b,
    float* __restrict__ pooled)
{
    __shared__ float ss[32][104];
    __shared__ float ws[A_][128];
    const int tid = threadIdx.x;
    const int row0 = blockIdx.x * 32;
    const int b = row0 >> 9;
    const int c4 = tid & 31, rg = tid >> 5;
    float4 acc[4];
    #pragma unroll
    for (int i = 0; i < 4; ++i) { acc[i].x = acc[i].y = acc[i].z = acc[i].w = 0.f; }

    for (int c = 0; c < 3; ++c) {
        const float* src = (c == 0) ? x : (c == 1) ? x1 : x2;
        for (int idx = tid; idx < 32 * 25; idx += 256) {
            const int r = idx / 25, k4 = idx % 25;
            *(float4*)&ss[r][k4 * 4] =
                *(const float4*)(src + (size_t)(row0 + r) * XP_ + k4 * 4);
        }
        for (int idx = tid; idx < A_ * 32; idx += 256) {
            const int k = idx >> 5, cc = idx & 31;
            *(float4*)&ws[k][cc * 4] =
                *(const float4*)(aggT + ((size_t)c * A_ + k) * 128 + cc * 4);
        }
        __syncthreads();
        #pragma unroll 5
        for (int k = 0; k < A_; k += 4) {
            float4 sv[4];
            #pragma unroll
            for (int i = 0; i < 4; ++i) sv[i] = *(float4*)&ss[rg * 4 + i][k];
            #pragma unroll
            for (int j = 0; j < 4; ++j) {
                float4 w4 = *(float4*)&ws[k + j][c4 * 4];
                #pragma unroll
                for (int i = 0; i < 4; ++i) {
                    const float sj = ((float*)&sv[i])[j];
                    acc[i].x += sj * w4.x; acc[i].y += sj * w4.y;
                    acc[i].z += sj * w4.z; acc[i].w += sj * w4.w;
                }
            }
        }
        __syncthreads();
    }

    float4 bias = {0.f, 0.f, 0.f, 0.f};
    if (c4 < 25) bias = ((const float4*)agg_b)[c4];
    float4 rs = {0.f, 0.f, 0.f, 0.f};
    #pragma unroll
    for (int i = 0; i < 4; ++i) {
        rs.x += fmaxf(acc[i].x + bias.x, 0.f);
        rs.y += fmaxf(acc[i].y + bias.y, 0.f);
        rs.z += fmaxf(acc[i].z + bias.z, 0.f);
        rs.w += fmaxf(acc[i].w + bias.w, 0.f);
    }
    float* red = &ss[0][0];
    __syncthreads();
    *(float4*)&red[rg * 128 + c4 * 4] = rs;
    __syncthreads();
    if (rg == 0 && c4 < 25) {
        float4 tot = {0.f, 0.f, 0.f, 0.f};
        #pragma unroll
        for (int g = 0; g < 8; ++g) {
            float4 v = *(float4*)&red[g * 128 + c4 * 4];
            tot.x += v.x; tot.y += v.y; tot.z += v.z; tot.w += v.w;
        }
        atomicAdd(&pooled[b * A_ + c4 * 4 + 0], tot.x);
        atomicAdd(&pooled[b * A_ + c4 * 4 + 1], tot.y);
        atomicAdd(&pooled[b * A_ + c4 * 4 + 2], tot.z);
        atomicAdd(&pooled[b * A_ + c4 * 4 + 3], tot.w);
    }
}

// ---------------- K7: logits = (pooled/valid_len) @ cls^T + b
__global__ __launch_bounds__(64) void k_logits(
    const float* __restrict__ pooled, const float* __restrict__ cls_w,
    const float* __restrict__ cls_b, const int* __restrict__ mask_ids,
    float* __restrict__ out)
{
    const int tid = threadIdx.x;
    if (tid < B_ * P_) {
        const int b = tid / P_, p = tid % P_;
        int vs = 0;
        for (int l = 0; l < L_; ++l) vs += mask_ids[b * L_ + l];
        float inv = 1.0f / (float)max(vs, 1);
        float acc = cls_b[p];
        #pragma unroll 4
        for (int a = 0; a < A_; ++a) acc += (pooled[b * A_ + a] * inv) * cls_w[p * A_ + a];
        out[b * P_ + p] = acc;
    }
}

extern "C" void kernel_launch(void* const* d_in, const int* in_sizes, int n_in,
                              void* d_out, int out_size, void* d_ws, size_t ws_size,
                              hipStream_t stream) {
    const float* seq    = (const float*)d_in[0];
    const float* syn    = (const float*)d_in[1];
    const float* ln_a   = (const float*)d_in[2];
    const float* ln_b   = (const float*)d_in[3];
    const float* Wxx_w  = (const float*)d_in[4];
    const float* Wxx_b  = (const float*)d_in[5];
    const float* q_w    = (const float*)d_in[6];
    const float* q_b    = (const float*)d_in[7];
    const float* k_w    = (const float*)d_in[8];
    const float* k_b    = (const float*)d_in[9];
    const float* W_w    = (const float*)d_in[10];
    const float* W_b    = (const float*)d_in[11];
    const float* Wx_w   = (const float*)d_in[12];
    const float* Wx_b   = (const float*)d_in[13];
    const float* agg_w  = (const float*)d_in[14];
    const float* agg_b  = (const float*)d_in[15];
    const float* cls_w  = (const float*)d_in[16];
    const float* cls_b  = (const float*)d_in[17];
    const int* mask_ids = (const int*)d_in[18];
    const int* src_mask = (const int*)d_in[19];
    float* out = (float*)d_out;

    float* ws = (float*)d_ws;
    size_t off = 0;
    float* xp     = ws + off; off += (size_t)B_ * L_ * XP_;
    float* x1p    = ws + off; off += (size_t)B_ * L_ * XP_;
    float* x2p    = ws + off; off += (size_t)B_ * L_ * XP_;
    float* axb    = ws + off; off += (size_t)B_ * L_ * XP_;
    float* qt     = ws + off; off += (size_t)B_ * L_ * A_;
    float* kt     = ws + off; off += (size_t)B_ * L_ * A_;
    float* es     = ws + off; off += (size_t)B_ * H_ * L_ * L_;
    float* Vv     = ws + off; off += (size_t)B_ * L_;
    float* T      = ws + off; off += (size_t)B_ * A_;
    float* S      = ws + off; off += (size_t)B_ * A_;
    float* pooled = ws + off; off += (size_t)B_ * A_;
    float* wT     = ws + off; off += (size_t)D_ * 128;
    float* aggT   = ws + off; off += (size_t)3 * A_ * 128;
    float* qkT    = ws + off; off += (size_t)A_ * 256;
    float* WT     = ws + off; off += (size_t)A_ * 128;

    k_wprep<<<(D_ * 128) / 256, 256, 0, stream>>>(Wxx_w, wT);
    k_aggprep<<<(3 * A_ * 128) / 256, 256, 0, stream>>>(agg_w, aggT);
    k_qkprep<<<(A_ * 256) / 256, 256, 0, stream>>>(q_w, k_w, qkT);
    k_wprep2<<<(A_ * 128) / 256, 256, 0, stream>>>(W_w, WT);
    k_lnx<<<(B_ * L_) / 32, 256, 0, stream>>>(seq, ln_a, ln_b, wT, Wxx_b, xp);
    k_qkg<<<dim3((B_ * L_) / 32, 2), 256, 0, stream>>>(xp, qkT, q_b, k_b, qt, kt);
    k_sgemm<<<dim3(8, 8, B_ * H_), 256, 0, stream>>>(qt, kt, syn, src_mask, es);
    k_softmax<<<B_ * L_, 256, 0, stream>>>(Wx_w, es);
    k_axg<0><<<(B_ * L_) / 32, 256, 0, stream>>>(es, xp, nullptr, nullptr, nullptr, nullptr, axb);
    k_xw<<<(B_ * L_) / 32, 256, 0, stream>>>(axb, WT, W_b, x1p);
    k_extras<<<B_, 256, 0, stream>>>(x1p, Wx_w, Vv, T, S, pooled);
    k_axg<1><<<(B_ * L_) / 32, 256, 0, stream>>>(es + (size_t)L_ * L_, x1p, S, T, Vv, Wx_b, axb);
    k_xw<<<(B_ * L_) / 32, 256, 0, stream>>>(axb, WT, W_b, x2p);
    k_nodepool<<<(B_ * L_) / 32, 256, 0, stream>>>(xp, x1p, x2p, aggT, agg_b, pooled);
    k_logits<<<1, 64, 0, stream>>>(pooled, cls_w, cls_b, mask_ids, out);
}